// Round 2
// baseline (4025.548 us; speedup 1.0000x reference)
//
#include <hip/hip_runtime.h>
#include <math.h>

// Problem constants: B=64, S=256, IN_DIM=512, MEM=256, LAYERS=3, HEADS=8, TOP_K=200
// NROW = B*S = 16384.

__device__ __forceinline__ float blk_sum(float v, float* sb) {
#pragma unroll
    for (int o = 32; o; o >>= 1) v += __shfl_down(v, o);
    int lane = threadIdx.x & 63, w = threadIdx.x >> 6;
    if (!lane) sb[w] = v;
    __syncthreads();
    float r = sb[0] + sb[1] + sb[2] + sb[3];
    __syncthreads();
    return r;
}

__device__ __forceinline__ float blk_max(float v, float* sb) {
#pragma unroll
    for (int o = 32; o; o >>= 1) v = fmaxf(v, __shfl_down(v, o));
    int lane = threadIdx.x & 63, w = threadIdx.x >> 6;
    if (!lane) sb[w] = v;
    __syncthreads();
    float r = fmaxf(fmaxf(sb[0], sb[1]), fmaxf(sb[2], sb[3]));
    __syncthreads();
    return r;
}

__global__ void init_flags(int* flags) {
    if (threadIdx.x < 3) flags[threadIdx.x] = 0;
}

// Sniff score_mask storage: bool-u8 / int32 / float32. Scans first 4MB (always in-bounds).
__global__ void detect_mask(const unsigned int* __restrict__ w, int nwords, int* flags) {
    int stride = gridDim.x * blockDim.x;
    int l_u8 = 0, l_f32 = 0, l_nz = 0;
    for (int i = blockIdx.x * blockDim.x + threadIdx.x; i < nwords; i += stride) {
        unsigned v = w[i];
        if (v) {
            l_nz = 1;
            if (v == 0x3F800000u) l_f32 = 1;
            else if (v > 1u) l_u8 = 1;
        }
    }
    if (__ballot(l_u8) && (threadIdx.x & 63) == 0) atomicOr(&flags[0], 1);
    if (__ballot(l_f32) && (threadIdx.x & 63) == 0) atomicOr(&flags[1], 1);
    if (__ballot(l_nz) && (threadIdx.x & 63) == 0) atomicOr(&flags[2], 1);
}

// pad[b,i] = score_mask[b,0,i,0]  (column 0 is never padded since lengths>=32)
__global__ void extract_pad(const void* __restrict__ mask, const int* __restrict__ flags,
                            unsigned char* __restrict__ pad) {
    int b = blockIdx.x, i = threadIdx.x;
    int v;
    size_t idx = (size_t)b * 65536 + (size_t)i * 256;
    if (flags[0]) v = ((const unsigned char*)mask)[idx] != 0;
    else if (flags[2]) v = ((const unsigned int*)mask)[idx] != 0;
    else v = 0;
    pad[b * 256 + i] = (unsigned char)v;
}

// denom[row] = sum_j x[row,j] + 1
__global__ void rowsum_plus1(const float* __restrict__ x, float* __restrict__ out) {
    __shared__ float sb[4];
    int row = blockIdx.x;
    float v = x[(size_t)row * 256 + threadIdx.x];
    float r = blk_sum(v, sb);
    if (!threadIdx.x) out[row] = r + 1.f;
}

__global__ void copy_cols(const float* __restrict__ src, int lds_, float* __restrict__ dst,
                          int ldd, int width) {
    int row = blockIdx.x;
    for (int c = threadIdx.x; c < width; c += 256)
        dst[(size_t)row * ldd + c] = src[(size_t)row * lds_ + c];
}

// Copy head-slice of weight [D, dk] into zero-padded wpad [D, 128]; block 0 also pads bias.
__global__ void pad_weight(const float* __restrict__ w, const float* __restrict__ b,
                           int ldw, int off, int dk,
                           float* __restrict__ wpad, float* __restrict__ bpad) {
    int d = blockIdx.x, t = threadIdx.x;
    wpad[d * 128 + t] = (t < dk) ? w[(size_t)d * ldw + off + t] : 0.f;
    if (d == 0) bpad[t] = (t < dk) ? b[off + t] : 0.f;
}

// Tiled fp32 GEMM. C[m,n] = alpha * sum_k A[m,k]*op(B)[k,n] (+ bias[n])
// op(B) = B (NN) or B^T (NT, B stored [n,k]). Batched via blockIdx.z:
//   offA = z*sA, offB = z*sB, offC = z*sC.
template <bool TRANSB>
__global__ __launch_bounds__(256) void gemm_tile(
    const float* __restrict__ A, const float* __restrict__ B,
    const float* __restrict__ bias, float* __restrict__ C,
    int K, int lda, int ldb, int ldc,
    long sA, long sB, long sC, float alpha) {
    int z = blockIdx.z;
    const float* Ab = A + (size_t)z * sA;
    const float* Bb = B + (size_t)z * sB;
    float* Cb = C + (size_t)z * sC;
    int m0 = blockIdx.y * 64, n0 = blockIdx.x * 64;
    __shared__ float As[16][64];
    __shared__ float Bs[16][64];
    int t = threadIdx.x;
    int tx = t & 15, ty = t >> 4;
    int am = t >> 2, ak = (t & 3) << 2;
    float acc[4][4] = {{0.f}};
    for (int k0 = 0; k0 < K; k0 += 16) {
        float4 av = *(const float4*)(Ab + (size_t)(m0 + am) * lda + k0 + ak);
        float4 bv;
        if (!TRANSB) {
            bv = *(const float4*)(Bb + (size_t)(k0 + (t >> 4)) * ldb + n0 + ((t & 15) << 2));
        } else {
            bv = *(const float4*)(Bb + (size_t)(n0 + am) * ldb + k0 + ak);
        }
        __syncthreads();
        As[ak + 0][am] = av.x; As[ak + 1][am] = av.y;
        As[ak + 2][am] = av.z; As[ak + 3][am] = av.w;
        if (!TRANSB) {
            int bk = t >> 4, bn = (t & 15) << 2;
            Bs[bk][bn] = bv.x; Bs[bk][bn + 1] = bv.y;
            Bs[bk][bn + 2] = bv.z; Bs[bk][bn + 3] = bv.w;
        } else {
            Bs[ak + 0][am] = bv.x; Bs[ak + 1][am] = bv.y;
            Bs[ak + 2][am] = bv.z; Bs[ak + 3][am] = bv.w;
        }
        __syncthreads();
#pragma unroll
        for (int kk = 0; kk < 16; ++kk) {
            float4 a4 = *(const float4*)&As[kk][ty << 2];
            float4 b4 = *(const float4*)&Bs[kk][tx << 2];
            acc[0][0] += a4.x * b4.x; acc[0][1] += a4.x * b4.y;
            acc[0][2] += a4.x * b4.z; acc[0][3] += a4.x * b4.w;
            acc[1][0] += a4.y * b4.x; acc[1][1] += a4.y * b4.y;
            acc[1][2] += a4.y * b4.z; acc[1][3] += a4.y * b4.w;
            acc[2][0] += a4.z * b4.x; acc[2][1] += a4.z * b4.y;
            acc[2][2] += a4.z * b4.z; acc[2][3] += a4.z * b4.w;
            acc[3][0] += a4.w * b4.x; acc[3][1] += a4.w * b4.y;
            acc[3][2] += a4.w * b4.z; acc[3][3] += a4.w * b4.w;
        }
    }
    float4 bias4 = make_float4(0.f, 0.f, 0.f, 0.f);
    if (bias) bias4 = *(const float4*)(bias + n0 + (tx << 2));
#pragma unroll
    for (int i = 0; i < 4; ++i) {
        float4 o;
        o.x = acc[i][0] * alpha + bias4.x;
        o.y = acc[i][1] * alpha + bias4.y;
        o.z = acc[i][2] * alpha + bias4.z;
        o.w = acc[i][3] * alpha + bias4.w;
        *(float4*)(Cb + (size_t)(m0 + (ty << 2) + i) * ldc + n0 + (tx << 2)) = o;
    }
}

// Masked softmax for ONE head [64,256,256]; accumulates head-sum into a[b,i,j].
__global__ void softmax_headsum(const float* __restrict__ scores, const unsigned char* __restrict__ pad,
                                float* __restrict__ a, int accum) {
    __shared__ float sb[4];
    int row = blockIdx.x;
    int b = row >> 8, i = row & 255, j = threadIdx.x;
    bool padi = pad[row] != 0;
    bool padj = pad[(b << 8) | j] != 0;
    float acc = accum ? a[(size_t)row * 256 + j] : 0.f;
    if (!padi) {
        float s = scores[((size_t)b * 256 + i) * 256 + j];
        if (padj) s = -1e9f;
        float m = blk_max(s, sb);
        float p = expf(s - m);
        float sum = blk_sum(p, sb);
        acc += p / sum;
    } else {
        acc = 0.f;
    }
    a[(size_t)row * 256 + j] = acc;
}

// Exact 200th-largest per batch via 4-pass radix select on float bits (values >= 0).
__global__ void topk_thr(const float* __restrict__ a, float* __restrict__ thr) {
    __shared__ unsigned int hist[256];
    __shared__ unsigned int s_prefix;
    __shared__ int s_k;
    int b = blockIdx.x, t = threadIdx.x;
    const unsigned int* ab = (const unsigned int*)(a + (size_t)b * 65536);
    if (!t) { s_prefix = 0; s_k = 200; }
    for (int pass = 0; pass < 4; ++pass) {
        hist[t] = 0;
        __syncthreads();
        unsigned pfx = s_prefix;
        int shift = 24 - 8 * pass;
        for (int idx = t; idx < 65536; idx += 256) {
            unsigned u = ab[idx];
            if (pass == 0 || (u >> (shift + 8)) == pfx)
                atomicAdd(&hist[(u >> shift) & 255], 1u);
        }
        __syncthreads();
        if (!t) {
            int k = s_k;
            unsigned c = 0;
            int bin = 255;
            for (; bin >= 0; --bin) {
                c += hist[bin];
                if ((int)c >= k) break;
            }
            if (bin < 0) bin = 0;
            s_k = k - (int)(c - hist[bin]);
            s_prefix = (pfx << 8) | (unsigned)bin;
        }
        __syncthreads();
    }
    if (!t) thr[b] = __uint_as_float(s_prefix);
}

// a2 = a * (sel + sel^T off-diag, 1 on diag); denom = rowsum(a2)+1
__global__ void select_apply(const float* __restrict__ a, const float* __restrict__ thr,
                             float* __restrict__ a2, float* __restrict__ denom) {
    __shared__ float sb[4];
    int row = blockIdx.x;
    int b = row >> 8, i = row & 255, j = threadIdx.x;
    const float* ab = a + (size_t)b * 65536;
    float tb = thr[b];
    float v = ab[i * 256 + j];
    float vt = ab[j * 256 + i];
    float sel = (v >= tb ? 1.f : 0.f) + (vt >= tb ? 1.f : 0.f);
    if (i == j) sel = 1.f;
    float av = v * sel;
    a2[(size_t)row * 256 + j] = av;
    float r = blk_sum(av, sb);
    if (!j) denom[row] = r + 1.f;
}

// out[row, coloff+j] = relu((t+b)/denom) + z + b
__global__ void gcn_epilogue(const float* __restrict__ t, const float* __restrict__ z,
                             const float* __restrict__ bias, const float* __restrict__ denom,
                             float* __restrict__ out, int ldo, int coloff) {
    int row = blockIdx.x, j = threadIdx.x;
    float bj = bias[j];
    float d = denom[row];
    size_t n = (size_t)row * 256 + j;
    float u = (t[n] + bj) / d;
    out[(size_t)row * ldo + coloff + j] = fmaxf(u, 0.f) + z[n] + bj;
}

extern "C" void kernel_launch(void* const* d_in, const int* in_sizes, int n_in,
                              void* d_out, int out_size, void* d_ws, size_t ws_size,
                              hipStream_t stream) {
    const float* adj = (const float*)d_in[0];
    const float* x0 = (const float*)d_in[1];
    const void* mask = d_in[2];
    const float* W0w = (const float*)d_in[3];
    const float* W0b = (const float*)d_in[4];
    const float* W1w = (const float*)d_in[5];
    const float* W1b = (const float*)d_in[6];
    const float* W2w = (const float*)d_in[7];
    const float* W2b = (const float*)d_in[8];
    const float* qws[2] = {(const float*)d_in[9], (const float*)d_in[13]};
    const float* qbs[2] = {(const float*)d_in[10], (const float*)d_in[14]};
    const float* kws[2] = {(const float*)d_in[11], (const float*)d_in[15]};
    const float* kbs[2] = {(const float*)d_in[12], (const float*)d_in[16]};

    char* base = (char*)d_ws;
    size_t cur = 0;
    auto alloc = [&](size_t bytes) -> void* {
        cur = (cur + 1023) & ~(size_t)1023;
        void* p = base + cur;
        cur += bytes;
        return p;
    };
    const size_t NROW = 16384;  // B*S
    int* flags = (int*)alloc(3 * sizeof(int));
    unsigned char* pad = (unsigned char*)alloc(NROW);
    float* denom = (float*)alloc(NROW * 4);
    float* thr = (float*)alloc(64 * 4);
    float* qwpad = (float*)alloc(1024 * 128 * 4);
    float* kwpad = (float*)alloc(1024 * 128 * 4);
    float* qbpad = (float*)alloc(128 * 4);
    float* kbpad = (float*)alloc(128 * 4);
    float* xbuf = (float*)alloc(NROW * 1024 * 4);        // [16384,1024] concat features
    float* regionA = (float*)alloc(NROW * 256 * 4);      // tz | (qh, kh)
    float* regionB = (float*)alloc(NROW * 256 * 4);      // tt | scores (one head)
    float* a = (float*)alloc(NROW * 256 * 4);
    float* a2 = (float*)alloc(NROW * 256 * 4);
    if (ws_size < cur) return;  // clean failure instead of device fault

    float* tz = regionA;
    float* qh = regionA;                    // [16384,128]
    float* kh = regionA + NROW * 128;       // [16384,128]
    float* tt = regionB;
    float* scores = regionB;                // [64,256,256]

    init_flags<<<1, 64, 0, stream>>>(flags);
    detect_mask<<<64, 256, 0, stream>>>((const unsigned int*)mask, 1048576, flags);
    extract_pad<<<64, 256, 0, stream>>>(mask, flags, pad);
    rowsum_plus1<<<16384, 256, 0, stream>>>(adj, denom);
    copy_cols<<<16384, 256, 0, stream>>>(x0, 512, xbuf, 1024, 512);

    // D per attention layer, dk per head
    const int Ds[2] = {768, 1024};
    const int dks[2] = {96, 128};
    const float* Wls[3] = {W0w, W1w, W2w};
    const float* bls[3] = {W0b, W1b, W2b};
    const int Ks[3] = {512, 768, 1024};

    for (int l = 0; l < 3; ++l) {
        // tz = x @ Wl  (x = xbuf[:, 0:Ks[l]], ld 1024)
        gemm_tile<false><<<dim3(4, 256, 1), 256, 0, stream>>>(
            xbuf, Wls[l], nullptr, tz, Ks[l], 1024, 256, 256, 0, 0, 0, 1.f);
        // tt = adjacency @ tz  (adjacency = adj for l=0 else a2), batched over 64
        const float* A = (l == 0) ? adj : a2;
        gemm_tile<false><<<dim3(4, 4, 64), 256, 0, stream>>>(
            A, tz, nullptr, tt, 256, 256, 256, 256, 65536, 65536, 65536, 1.f);
        // epilogue -> xbuf[:, Ks[l] : Ks[l]+256]  (or d_out for l=2)
        if (l < 2) {
            gcn_epilogue<<<16384, 256, 0, stream>>>(tt, tz, bls[l], denom, xbuf, 1024, Ks[l]);
        } else {
            gcn_epilogue<<<16384, 256, 0, stream>>>(tt, tz, bls[l], denom, (float*)d_out, 256, 0);
            break;
        }

        // ---- attention l: one head at a time (dk padded to 128 with zeros)
        int D = Ds[l], dk = dks[l];
        float scale = 1.f / sqrtf((float)dk);
        for (int h = 0; h < 8; ++h) {
            pad_weight<<<D, 128, 0, stream>>>(qws[l], qbs[l], D, h * dk, dk, qwpad, qbpad);
            pad_weight<<<D, 128, 0, stream>>>(kws[l], kbs[l], D, h * dk, dk, kwpad, kbpad);
            gemm_tile<false><<<dim3(2, 256, 1), 256, 0, stream>>>(
                xbuf, qwpad, qbpad, qh, D, 1024, 128, 128, 0, 0, 0, 1.f);
            gemm_tile<false><<<dim3(2, 256, 1), 256, 0, stream>>>(
                xbuf, kwpad, kbpad, kh, D, 1024, 128, 128, 0, 0, 0, 1.f);
            // scores[b,i,j] = scale * qh[b,i,:] . kh[b,j,:]   (K=128; pad cols are 0)
            gemm_tile<true><<<dim3(4, 4, 64), 256, 0, stream>>>(
                qh, kh, nullptr, scores, 128, 128, 128, 256,
                (long)256 * 128, (long)256 * 128, 65536, scale);
            softmax_headsum<<<16384, 256, 0, stream>>>(scores, pad, a, h ? 1 : 0);
        }
        topk_thr<<<64, 256, 0, stream>>>(a, thr);
        select_apply<<<16384, 256, 0, stream>>>(a, thr, a2, denom);
    }
}

// Round 3
// 3429.715 us; speedup vs baseline: 1.1737x; 1.1737x over previous
//
#include <hip/hip_runtime.h>
#include <math.h>

// B=64, S=256, IN_DIM=512, MEM=256, LAYERS=3, HEADS=8, TOP_K=200. NROW=16384.

typedef __attribute__((ext_vector_type(8))) short s16x8;
typedef __attribute__((ext_vector_type(4))) float f32x4;

__device__ __forceinline__ short f2bf(float x) {
    unsigned u = __float_as_uint(x);
    u += 0x7FFF + ((u >> 16) & 1);  // rn-even
    return (short)(u >> 16);
}
__device__ __forceinline__ float bf2f(short h) {
    return __uint_as_float(((unsigned)(unsigned short)h) << 16);
}

__device__ __forceinline__ float blk_sum(float v, float* sb) {
#pragma unroll
    for (int o = 32; o; o >>= 1) v += __shfl_down(v, o);
    int lane = threadIdx.x & 63, w = threadIdx.x >> 6;
    if (!lane) sb[w] = v;
    __syncthreads();
    float r = sb[0] + sb[1] + sb[2] + sb[3];
    __syncthreads();
    return r;
}

__global__ void init_flags(int* flags) {
    if (threadIdx.x < 3) flags[threadIdx.x] = 0;
}

__global__ void detect_mask(const unsigned int* __restrict__ w, int nwords, int* flags) {
    int stride = gridDim.x * blockDim.x;
    int l_u8 = 0, l_f32 = 0, l_nz = 0;
    for (int i = blockIdx.x * blockDim.x + threadIdx.x; i < nwords; i += stride) {
        unsigned v = w[i];
        if (v) {
            l_nz = 1;
            if (v == 0x3F800000u) l_f32 = 1;
            else if (v > 1u) l_u8 = 1;
        }
    }
    if (__ballot(l_u8) && (threadIdx.x & 63) == 0) atomicOr(&flags[0], 1);
    if (__ballot(l_f32) && (threadIdx.x & 63) == 0) atomicOr(&flags[1], 1);
    if (__ballot(l_nz) && (threadIdx.x & 63) == 0) atomicOr(&flags[2], 1);
}

__global__ void extract_pad(const void* __restrict__ mask, const int* __restrict__ flags,
                            unsigned char* __restrict__ pad) {
    int b = blockIdx.x, i = threadIdx.x;
    int v;
    size_t idx = (size_t)b * 65536 + (size_t)i * 256;
    if (flags[0]) v = ((const unsigned char*)mask)[idx] != 0;
    else if (flags[2]) v = ((const unsigned int*)mask)[idx] != 0;
    else v = 0;
    pad[b * 256 + i] = (unsigned char)v;
}

__global__ void rowsum_plus1(const float* __restrict__ x, float* __restrict__ out) {
    __shared__ float sb[4];
    int row = blockIdx.x;
    float v = x[(size_t)row * 256 + threadIdx.x];
    float r = blk_sum(v, sb);
    if (!threadIdx.x) out[row] = r + 1.f;
}

__global__ void copy_cols(const float* __restrict__ src, int lds_, float* __restrict__ dst,
                          int ldd, int width) {
    int row = blockIdx.x;
    for (int c = threadIdx.x; c < width; c += 256)
        dst[(size_t)row * ldd + c] = src[(size_t)row * lds_ + c];
}

// out[C][R] = in[R][C]^T. R,C multiples of 32.
__global__ void transpose_f32(const float* __restrict__ in, float* __restrict__ out,
                              int R, int C) {
    __shared__ float tile[32][33];
    int c0 = blockIdx.x * 32, r0 = blockIdx.y * 32;
    int tx = threadIdx.x & 31, ty = threadIdx.x >> 5;
    for (int rr = ty; rr < 32; rr += 8)
        tile[rr][tx] = in[(size_t)(r0 + rr) * C + c0 + tx];
    __syncthreads();
    for (int rr = ty; rr < 32; rr += 8)
        out[(size_t)(c0 + rr) * R + r0 + tx] = tile[tx][rr];
}

// Split-bf16 MFMA GEMM: C = alpha*(A @ B^T) (+bias). A [M,K] lda, B [N,K] ldb (k-contiguous).
// fp32 inputs split to hi/lo bf16; acc = AhBh + AhBl + AlBh (fp32-class accuracy).
// mode 0: write C (ldc,+coloff) and/or CT[b][n][m'] (batch-transposed, N must be 256).
// mode 1: fused GCN epilogue: out = relu((acc+bias[n])/denom[row]) + CT[b][n][m'] + bias[n].
// Batched via blockIdx.z: A+=z*sA, B+=z*sB, C+=z*sC, CT+=z*sCT, denom+=z*sD.
__global__ __launch_bounds__(256) void mgemm(
    const float* __restrict__ A, const float* __restrict__ B,
    const float* __restrict__ bias, float* __restrict__ C, float* __restrict__ CT,
    const float* __restrict__ denom,
    int K, int N, int lda, int ldb, int ldc, int coloff,
    long sA, long sB, long sC, long sCT, long sD, float alpha, int mode) {
    int z = blockIdx.z;
    const float* Ab = A + (size_t)z * sA;
    const float* Bb = B + (size_t)z * sB;
    float* Cb = C ? (C + (size_t)z * sC) : nullptr;
    float* CTb = CT ? (CT + (size_t)z * sCT) : nullptr;
    const float* Db = denom ? (denom + (size_t)z * sD) : nullptr;
    int m0 = blockIdx.y * 128, n0 = blockIdx.x * 128;
    __shared__ short lds[16384];  // Ah[0:4096] Al[4096:] Bh[8192:] Bl[12288:] (shorts)
    int t = threadIdx.x;
    int lane = t & 63, w = t >> 6;
    int wm = w >> 1, wn = w & 1;
    f32x4 acc[4][4];
#pragma unroll
    for (int i = 0; i < 4; ++i)
#pragma unroll
        for (int j = 0; j < 4; ++j)
            acc[i][j] = (f32x4){0.f, 0.f, 0.f, 0.f};

    for (int k0 = 0; k0 < K; k0 += 32) {
        __syncthreads();
#pragma unroll
        for (int s = t; s < 512; s += 256) {
            int tile = s >> 6, sl = s & 63;
            int mi = tile * 16 + (sl & 15);
            int kb = ((sl >> 4) & 3) * 8;
            int koff = k0 + kb;
            {
                const float* ap = Ab + (size_t)(m0 + mi) * lda + koff;
                float4 x0 = *(const float4*)ap;
                float4 x1 = *(const float4*)(ap + 4);
                float vv[8] = {x0.x, x0.y, x0.z, x0.w, x1.x, x1.y, x1.z, x1.w};
                s16x8 hv, lv;
#pragma unroll
                for (int r = 0; r < 8; ++r) {
                    short h = f2bf(vv[r]);
                    hv[r] = h;
                    lv[r] = f2bf(vv[r] - bf2f(h));
                }
                *(s16x8*)&lds[s * 8] = hv;
                *(s16x8*)&lds[4096 + s * 8] = lv;
            }
            {
                int ni = n0 + mi;
                float4 x0 = make_float4(0.f, 0.f, 0.f, 0.f);
                float4 x1 = make_float4(0.f, 0.f, 0.f, 0.f);
                if (ni < N) {
                    const float* bp = Bb + (size_t)ni * ldb + koff;
                    x0 = *(const float4*)bp;
                    x1 = *(const float4*)(bp + 4);
                }
                float vv[8] = {x0.x, x0.y, x0.z, x0.w, x1.x, x1.y, x1.z, x1.w};
                s16x8 hv, lv;
#pragma unroll
                for (int r = 0; r < 8; ++r) {
                    short h = f2bf(vv[r]);
                    hv[r] = h;
                    lv[r] = f2bf(vv[r] - bf2f(h));
                }
                *(s16x8*)&lds[8192 + s * 8] = hv;
                *(s16x8*)&lds[12288 + s * 8] = lv;
            }
        }
        __syncthreads();
        s16x8 ah[4], al4[4], bh[4], bl4[4];
#pragma unroll
        for (int i = 0; i < 4; ++i) {
            int off = ((wm * 4 + i) * 64 + lane) * 8;
            ah[i] = *(const s16x8*)&lds[off];
            al4[i] = *(const s16x8*)&lds[4096 + off];
        }
#pragma unroll
        for (int j = 0; j < 4; ++j) {
            int off = ((wn * 4 + j) * 64 + lane) * 8;
            bh[j] = *(const s16x8*)&lds[8192 + off];
            bl4[j] = *(const s16x8*)&lds[12288 + off];
        }
#pragma unroll
        for (int i = 0; i < 4; ++i)
#pragma unroll
            for (int j = 0; j < 4; ++j) {
                acc[i][j] = __builtin_amdgcn_mfma_f32_16x16x32_bf16(ah[i], bh[j], acc[i][j], 0, 0, 0);
                acc[i][j] = __builtin_amdgcn_mfma_f32_16x16x32_bf16(ah[i], bl4[j], acc[i][j], 0, 0, 0);
                acc[i][j] = __builtin_amdgcn_mfma_f32_16x16x32_bf16(al4[i], bh[j], acc[i][j], 0, 0, 0);
            }
    }

    int col = lane & 15, quad = lane >> 4;
#pragma unroll
    for (int i = 0; i < 4; ++i)
#pragma unroll
        for (int j = 0; j < 4; ++j) {
            int mg = m0 + wm * 64 + i * 16 + quad * 4;
            int ng = n0 + wn * 64 + j * 16 + col;
            if (ng >= N) continue;
            f32x4 v = acc[i][j];
            if (mode == 0) {
                float bz = bias ? bias[ng] : 0.f;
                float o0 = v[0] * alpha + bz, o1 = v[1] * alpha + bz;
                float o2 = v[2] * alpha + bz, o3 = v[3] * alpha + bz;
                if (Cb) {
                    Cb[(size_t)(mg + 0) * ldc + coloff + ng] = o0;
                    Cb[(size_t)(mg + 1) * ldc + coloff + ng] = o1;
                    Cb[(size_t)(mg + 2) * ldc + coloff + ng] = o2;
                    Cb[(size_t)(mg + 3) * ldc + coloff + ng] = o3;
                }
                if (CTb) {
                    float4 w4 = make_float4(o0, o1, o2, o3);
                    *(float4*)(CTb + (size_t)(mg >> 8) * 65536 + (size_t)ng * 256 + (mg & 255)) = w4;
                }
            } else {
                float bz = bias[ng];
                float4 sk = *(const float4*)(CTb + (size_t)(mg >> 8) * 65536 + (size_t)ng * 256 + (mg & 255));
                float skv[4] = {sk.x, sk.y, sk.z, sk.w};
#pragma unroll
                for (int r = 0; r < 4; ++r) {
                    float u = (v[r] + bz) / Db[mg + r];
                    Cb[(size_t)(mg + r) * ldc + coloff + ng] = fmaxf(u, 0.f) + skv[r] + bz;
                }
            }
        }
}

// One head's masked softmax, accumulated head-sum into a. One wave per row, 4 rows/block.
__global__ void softmax_headsum_w(const float* __restrict__ scores,
                                  const unsigned char* __restrict__ pad,
                                  float* __restrict__ a, int accum) {
    int row = blockIdx.x * 4 + (threadIdx.x >> 6);
    int lane = threadIdx.x & 63;
    int b = row >> 8;
    float* arow = a + (size_t)row * 256;
    if (pad[row]) {
        if (!accum) ((float4*)arow)[lane] = make_float4(0.f, 0.f, 0.f, 0.f);
        return;
    }
    float4 s = ((const float4*)(scores + (size_t)row * 256))[lane];
    unsigned pw = *(const unsigned*)(pad + (b << 8) + lane * 4);
    if (pw & 0x000000FFu) s.x = -1e9f;
    if (pw & 0x0000FF00u) s.y = -1e9f;
    if (pw & 0x00FF0000u) s.z = -1e9f;
    if (pw & 0xFF000000u) s.w = -1e9f;
    float m = fmaxf(fmaxf(s.x, s.y), fmaxf(s.z, s.w));
#pragma unroll
    for (int o = 32; o; o >>= 1) m = fmaxf(m, __shfl_xor(m, o));
    float e0 = expf(s.x - m), e1 = expf(s.y - m), e2 = expf(s.z - m), e3 = expf(s.w - m);
    float sum = e0 + e1 + e2 + e3;
#pragma unroll
    for (int o = 32; o; o >>= 1) sum += __shfl_xor(sum, o);
    float inv = 1.f / sum;
    float4 r = make_float4(e0 * inv, e1 * inv, e2 * inv, e3 * inv);
    if (accum) {
        float4 p = ((float4*)arow)[lane];
        r.x += p.x; r.y += p.y; r.z += p.z; r.w += p.w;
    }
    ((float4*)arow)[lane] = r;
}

// ---- parallel exact top-200 radix select (4 byte-passes, hist at 1024-block parallelism)
__global__ void tk_init(unsigned* ghist, unsigned* prefix, int* krem) {
    int i = blockIdx.x * 256 + threadIdx.x;
    ghist[i] = 0;
    if (i < 64) { prefix[i] = 0; krem[i] = 200; }
}

__global__ void tk_hist(const float* __restrict__ a, const unsigned* __restrict__ prefix,
                        unsigned* __restrict__ ghist, int shift) {
    __shared__ unsigned h[256];
    int b = blockIdx.x >> 4, slice = blockIdx.x & 15;
    h[threadIdx.x] = 0;
    __syncthreads();
    unsigned pfx = prefix[b];
    const unsigned* ab = (const unsigned*)(a + (size_t)b * 65536) + slice * 4096;
    for (int i = threadIdx.x; i < 4096; i += 256) {
        unsigned u = ab[i];
        if ((shift == 24) || ((u >> (shift + 8)) == pfx)) atomicAdd(&h[(u >> shift) & 255], 1u);
    }
    __syncthreads();
    if (h[threadIdx.x]) atomicAdd(&ghist[b * 256 + threadIdx.x], h[threadIdx.x]);
}

__global__ void tk_pick(unsigned* __restrict__ ghist, unsigned* __restrict__ prefix,
                        int* __restrict__ krem, float* __restrict__ thr, int last) {
    __shared__ unsigned h[256];
    int b = blockIdx.x;
    h[threadIdx.x] = ghist[b * 256 + threadIdx.x];
    ghist[b * 256 + threadIdx.x] = 0;
    __syncthreads();
    if (!threadIdx.x) {
        int k = krem[b];
        unsigned c = 0;
        int bin = 255;
        for (; bin >= 0; --bin) { c += h[bin]; if ((int)c >= k) break; }
        if (bin < 0) bin = 0;
        krem[b] = k - (int)(c - h[bin]);
        unsigned p = (prefix[b] << 8) | (unsigned)bin;
        prefix[b] = p;
        if (last) thr[b] = __uint_as_float(p);
    }
}

// a2 = a * (sel + sel^T off-diag, 1 on diag); denom = rowsum(a2)+1
__global__ void select_apply(const float* __restrict__ a, const float* __restrict__ thr,
                             float* __restrict__ a2, float* __restrict__ denom) {
    __shared__ float sb[4];
    int row = blockIdx.x;
    int b = row >> 8, i = row & 255, j = threadIdx.x;
    const float* ab = a + (size_t)b * 65536;
    float tb = thr[b];
    float v = ab[i * 256 + j];
    float vt = ab[j * 256 + i];
    float sel = (v >= tb ? 1.f : 0.f) + (vt >= tb ? 1.f : 0.f);
    if (i == j) sel = 1.f;
    float av = v * sel;
    a2[(size_t)row * 256 + j] = av;
    float r = blk_sum(av, sb);
    if (!j) denom[row] = r + 1.f;
}

extern "C" void kernel_launch(void* const* d_in, const int* in_sizes, int n_in,
                              void* d_out, int out_size, void* d_ws, size_t ws_size,
                              hipStream_t stream) {
    const float* adj = (const float*)d_in[0];
    const float* x0 = (const float*)d_in[1];
    const void* mask = d_in[2];
    const float* Wls[3] = {(const float*)d_in[3], (const float*)d_in[5], (const float*)d_in[7]};
    const float* bls[3] = {(const float*)d_in[4], (const float*)d_in[6], (const float*)d_in[8]};
    const float* qws[2] = {(const float*)d_in[9], (const float*)d_in[13]};
    const float* qbs[2] = {(const float*)d_in[10], (const float*)d_in[14]};
    const float* kws[2] = {(const float*)d_in[11], (const float*)d_in[15]};
    const float* kbs[2] = {(const float*)d_in[12], (const float*)d_in[16]};

    char* base = (char*)d_ws;
    size_t cur = 0;
    auto alloc = [&](size_t bytes) -> void* {
        cur = (cur + 1023) & ~(size_t)1023;
        void* p = base + cur;
        cur += bytes;
        return p;
    };
    const size_t NROW = 16384;
    int* flags = (int*)alloc(3 * sizeof(int));
    unsigned char* pad = (unsigned char*)alloc(NROW);
    float* denom = (float*)alloc(NROW * 4);
    float* thr = (float*)alloc(64 * 4);
    unsigned* prefix = (unsigned*)alloc(64 * 4);
    int* krem = (int*)alloc(64 * 4);
    unsigned* ghist = (unsigned*)alloc(64 * 256 * 4);
    float* W0T = (float*)alloc(256 * 512 * 4);
    float* W1T = (float*)alloc(256 * 768 * 4);
    float* W2T = (float*)alloc(256 * 1024 * 4);
    float* qwT = (float*)alloc(1024 * 1024 * 4);
    float* kwT = (float*)alloc(1024 * 1024 * 4);
    float* xbuf = (float*)alloc(NROW * 1024 * 4);  // concat features [16384,1024]
    float* tzT = (float*)alloc(NROW * 256 * 4);    // [64][256][256]; reused as qh/kh in attn
    float* a = (float*)alloc(NROW * 256 * 4);
    float* a2 = (float*)alloc(NROW * 256 * 4);     // reused as scores during attn
    if (ws_size < cur) return;  // clean failure instead of device fault

    float* qh = tzT;                  // [16384, dk<=128]
    float* kh = tzT + NROW * 128;     // [16384, dk<=128]
    float* scores = a2;               // [64,256,256]
    const float* WTs[3] = {W0T, W1T, W2T};
    const int Ks[3] = {512, 768, 1024};

    init_flags<<<1, 64, 0, stream>>>(flags);
    detect_mask<<<64, 256, 0, stream>>>((const unsigned int*)mask, 1048576, flags);
    extract_pad<<<64, 256, 0, stream>>>(mask, flags, pad);
    rowsum_plus1<<<16384, 256, 0, stream>>>(adj, denom);
    copy_cols<<<16384, 256, 0, stream>>>(x0, 512, xbuf, 1024, 512);
    for (int l = 0; l < 3; ++l)
        transpose_f32<<<dim3(8, Ks[l] / 32), 256, 0, stream>>>(Wls[l], (float*)WTs[l], Ks[l], 256);

    for (int l = 0; l < 3; ++l) {
        // tzT[b][n][m'] = (x @ Wl)^T per batch (CT-only write)
        mgemm<<<dim3(2, 128, 1), 256, 0, stream>>>(
            xbuf, WTs[l], nullptr, nullptr, tzT, nullptr,
            Ks[l], 256, 1024, Ks[l], 0, 0, 0, 0, 0, 0, 0, 1.f, 0);
        // fused: out = relu((A@tz + b)/denom) + tz + b
        const float* Aadj = (l == 0) ? adj : a2;
        float* outp = (l < 2) ? xbuf : (float*)d_out;
        int ldo = (l < 2) ? 1024 : 256;
        int coff = (l < 2) ? Ks[l] : 0;
        mgemm<<<dim3(2, 2, 64), 256, 0, stream>>>(
            Aadj, tzT, bls[l], outp, tzT, denom,
            256, 256, 256, 256, ldo, coff, 65536, 65536, (long)256 * ldo, 65536, 256, 1.f, 1);
        if (l == 2) break;

        int D = Ks[l + 1], dk = D / 8;
        float scale = 1.f / sqrtf((float)dk);
        transpose_f32<<<dim3(D / 32, D / 32), 256, 0, stream>>>(qws[l], qwT, D, D);
        transpose_f32<<<dim3(D / 32, D / 32), 256, 0, stream>>>(kws[l], kwT, D, D);
        for (int h = 0; h < 8; ++h) {
            mgemm<<<dim3(1, 128, 1), 256, 0, stream>>>(
                xbuf, qwT + (size_t)h * dk * D, qbs[l] + h * dk, qh, nullptr, nullptr,
                D, dk, 1024, D, dk, 0, 0, 0, 0, 0, 0, 1.f, 0);
            mgemm<<<dim3(1, 128, 1), 256, 0, stream>>>(
                xbuf, kwT + (size_t)h * dk * D, kbs[l] + h * dk, kh, nullptr, nullptr,
                D, dk, 1024, D, dk, 0, 0, 0, 0, 0, 0, 1.f, 0);
            mgemm<<<dim3(2, 2, 64), 256, 0, stream>>>(
                qh, kh, nullptr, scores, nullptr, nullptr,
                dk, 256, dk, dk, 256, 0, (long)256 * dk, (long)256 * dk, 65536, 0, 0, scale, 0);
            softmax_headsum_w<<<4096, 256, 0, stream>>>(scores, pad, a, h ? 1 : 0);
        }
        tk_init<<<64, 256, 0, stream>>>(ghist, prefix, krem);
        for (int p = 0; p < 4; ++p) {
            tk_hist<<<1024, 256, 0, stream>>>(a, prefix, ghist, 24 - 8 * p);
            tk_pick<<<64, 256, 0, stream>>>(ghist, prefix, krem, thr, p == 3);
        }
        select_apply<<<16384, 256, 0, stream>>>(a, thr, a2, denom);
    }
}

// Round 4
// 1638.250 us; speedup vs baseline: 2.4572x; 2.0935x over previous
//
#include <hip/hip_runtime.h>
#include <math.h>

// B=64, S=256, IN_DIM=512, MEM=256, LAYERS=3, HEADS=8, TOP_K=200. NROW=16384.

typedef __attribute__((ext_vector_type(8))) short s16x8;
typedef __attribute__((ext_vector_type(4))) short s16x4;
typedef __attribute__((ext_vector_type(4))) float f32x4;

__device__ __forceinline__ short f2bf(float x) {
    unsigned u = __float_as_uint(x);
    u += 0x7FFF + ((u >> 16) & 1);  // rn-even
    return (short)(u >> 16);
}
__device__ __forceinline__ float bf2f(short h) {
    return __uint_as_float(((unsigned)(unsigned short)h) << 16);
}

__device__ __forceinline__ float blk_sum(float v, float* sb) {
#pragma unroll
    for (int o = 32; o; o >>= 1) v += __shfl_down(v, o);
    int lane = threadIdx.x & 63, w = threadIdx.x >> 6;
    if (!lane) sb[w] = v;
    __syncthreads();
    float r = sb[0] + sb[1] + sb[2] + sb[3];
    __syncthreads();
    return r;
}

__global__ void init_flags(int* flags) {
    if (threadIdx.x < 3) flags[threadIdx.x] = 0;
}

__global__ void detect_mask(const unsigned int* __restrict__ w, int nwords, int* flags) {
    int stride = gridDim.x * blockDim.x;
    int l_u8 = 0, l_f32 = 0, l_nz = 0;
    for (int i = blockIdx.x * blockDim.x + threadIdx.x; i < nwords; i += stride) {
        unsigned v = w[i];
        if (v) {
            l_nz = 1;
            if (v == 0x3F800000u) l_f32 = 1;
            else if (v > 1u) l_u8 = 1;
        }
    }
    if (__ballot(l_u8) && (threadIdx.x & 63) == 0) atomicOr(&flags[0], 1);
    if (__ballot(l_f32) && (threadIdx.x & 63) == 0) atomicOr(&flags[1], 1);
    if (__ballot(l_nz) && (threadIdx.x & 63) == 0) atomicOr(&flags[2], 1);
}

__global__ void extract_pad(const void* __restrict__ mask, const int* __restrict__ flags,
                            unsigned char* __restrict__ pad) {
    int b = blockIdx.x, i = threadIdx.x;
    int v;
    size_t idx = (size_t)b * 65536 + (size_t)i * 256;
    if (flags[0]) v = ((const unsigned char*)mask)[idx] != 0;
    else if (flags[2]) v = ((const unsigned int*)mask)[idx] != 0;
    else v = 0;
    pad[b * 256 + i] = (unsigned char)v;
}

__global__ void rowsum_plus1(const float* __restrict__ x, float* __restrict__ out) {
    __shared__ float sb[4];
    int row = blockIdx.x;
    float v = x[(size_t)row * 256 + threadIdx.x];
    float r = blk_sum(v, sb);
    if (!threadIdx.x) out[row] = r + 1.f;
}

// Split fp32 matrix rows into bf16 hi/lo arrays.
__global__ void split_mat(const float* __restrict__ src, int ldsrc, int width,
                          short* __restrict__ dh, short* __restrict__ dl, int ldd) {
    int row = blockIdx.x;
    for (int c = threadIdx.x; c < width; c += 256) {
        float v = src[(size_t)row * ldsrc + c];
        short h = f2bf(v);
        dh[(size_t)row * ldd + c] = h;
        dl[(size_t)row * ldd + c] = f2bf(v - bf2f(h));
    }
}

// outh/outl[C][R] = split(in[R][C]^T). R,C multiples of 32.
__global__ void transpose_split(const float* __restrict__ in,
                                short* __restrict__ outh, short* __restrict__ outl,
                                int R, int C) {
    __shared__ float tile[32][33];
    int c0 = blockIdx.x * 32, r0 = blockIdx.y * 32;
    int tx = threadIdx.x & 31, ty = threadIdx.x >> 5;
    for (int rr = ty; rr < 32; rr += 8)
        tile[rr][tx] = in[(size_t)(r0 + rr) * C + c0 + tx];
    __syncthreads();
    for (int rr = ty; rr < 32; rr += 8) {
        float v = tile[tx][rr];
        short h = f2bf(v);
        size_t o = (size_t)(c0 + rr) * R + r0 + tx;
        outh[o] = h;
        outl[o] = f2bf(v - bf2f(h));
    }
}

__global__ void pack_bias(const float* __restrict__ qb, const float* __restrict__ kb,
                          float* __restrict__ dst, int D) {
    int i = blockIdx.x * 256 + threadIdx.x;
    if (i < D) { dst[i] = qb[i]; dst[1024 + i] = kb[i]; }
}

// Split-bf16 MFMA GEMM on PRE-SPLIT inputs: acc = AhBh + AhBl + AlBh (fp32-class).
// A [M,K] lda (hi/lo bf16), B [N,K] ldb (hi/lo bf16, k-contiguous). 128x128 tile.
// mode 0: o = alpha*acc + bias[ng]; write to C (fp32), (Ch,Cl) split, and/or CT split
//         (CT layout [b=m/256][n][m%256], N must be 256 for CT).
// mode 1: o = relu((acc+bias[ng])/denom[mg]) + (CTh+CTl)[mg,ng] + bias[ng];
//         write to C fp32 (if C) else split (Ch,Cl).
// Per-z offsets (elements): A+=z*sA, B+=z*sB, bias+=z*sBias, C/Ch/Cl+=z*sC,
// CTh/CTl+=z*sCT, denom+=z*sD.
__global__ __launch_bounds__(256) void mgemm(
    const short* __restrict__ Ah, const short* __restrict__ Al,
    const short* __restrict__ Bh, const short* __restrict__ Bl,
    const float* __restrict__ bias,
    float* __restrict__ C, short* __restrict__ Ch, short* __restrict__ Cl,
    short* __restrict__ CTh, short* __restrict__ CTl,
    const float* __restrict__ denom,
    int K, int N, int lda, int ldb, int ldc, int coloff,
    long sA, long sB, long sBias, long sC, long sCT, long sD,
    float alpha, int mode) {
    int z = blockIdx.z;
    const short* Ahb = Ah + (size_t)z * sA;
    const short* Alb = Al + (size_t)z * sA;
    const short* Bhb = Bh + (size_t)z * sB;
    const short* Blb = Bl + (size_t)z * sB;
    int m0 = blockIdx.y * 128, n0 = blockIdx.x * 128;
    __shared__ short lds[16384];  // Ah[0:4096] Al[4096:] Bh[8192:] Bl[12288:]
    int t = threadIdx.x;
    int lane = t & 63, w = t >> 6;
    int wm = w >> 1, wn = w & 1;
    f32x4 acc[4][4];
#pragma unroll
    for (int i = 0; i < 4; ++i)
#pragma unroll
        for (int j = 0; j < 4; ++j)
            acc[i][j] = (f32x4){0.f, 0.f, 0.f, 0.f};

    for (int k0 = 0; k0 < K; k0 += 32) {
        __syncthreads();
#pragma unroll
        for (int s = t; s < 512; s += 256) {
            int tile = s >> 6, sl = s & 63;
            int mi = tile * 16 + (sl & 15);
            int koff = k0 + ((sl >> 4) & 3) * 8;
            {
                size_t off = (size_t)(m0 + mi) * lda + koff;
                *(s16x8*)&lds[s * 8] = *(const s16x8*)(Ahb + off);
                *(s16x8*)&lds[4096 + s * 8] = *(const s16x8*)(Alb + off);
            }
            {
                int ni = n0 + mi;
                s16x8 hv = {0, 0, 0, 0, 0, 0, 0, 0};
                s16x8 lv = {0, 0, 0, 0, 0, 0, 0, 0};
                if (ni < N) {
                    size_t off = (size_t)ni * ldb + koff;
                    hv = *(const s16x8*)(Bhb + off);
                    lv = *(const s16x8*)(Blb + off);
                }
                *(s16x8*)&lds[8192 + s * 8] = hv;
                *(s16x8*)&lds[12288 + s * 8] = lv;
            }
        }
        __syncthreads();
        s16x8 ah[4], al4[4], bh[4], bl4[4];
#pragma unroll
        for (int i = 0; i < 4; ++i) {
            int off = ((wm * 4 + i) * 64 + lane) * 8;
            ah[i] = *(const s16x8*)&lds[off];
            al4[i] = *(const s16x8*)&lds[4096 + off];
        }
#pragma unroll
        for (int j = 0; j < 4; ++j) {
            int off = ((wn * 4 + j) * 64 + lane) * 8;
            bh[j] = *(const s16x8*)&lds[8192 + off];
            bl4[j] = *(const s16x8*)&lds[12288 + off];
        }
#pragma unroll
        for (int i = 0; i < 4; ++i)
#pragma unroll
            for (int j = 0; j < 4; ++j) {
                acc[i][j] = __builtin_amdgcn_mfma_f32_16x16x32_bf16(ah[i], bh[j], acc[i][j], 0, 0, 0);
                acc[i][j] = __builtin_amdgcn_mfma_f32_16x16x32_bf16(ah[i], bl4[j], acc[i][j], 0, 0, 0);
                acc[i][j] = __builtin_amdgcn_mfma_f32_16x16x32_bf16(al4[i], bh[j], acc[i][j], 0, 0, 0);
            }
    }

    int col = lane & 15, quad = lane >> 4;
#pragma unroll
    for (int i = 0; i < 4; ++i)
#pragma unroll
        for (int j = 0; j < 4; ++j) {
            int mg = m0 + wm * 64 + i * 16 + quad * 4;
            int ng = n0 + wn * 64 + j * 16 + col;
            if (ng >= N) continue;
            f32x4 v = acc[i][j];
            if (mode == 0) {
                float bz = bias ? bias[(size_t)z * sBias + ng] : 0.f;
                float o[4];
#pragma unroll
                for (int r = 0; r < 4; ++r) o[r] = v[r] * alpha + bz;
                if (C) {
                    float* Cb = C + (size_t)z * sC;
#pragma unroll
                    for (int r = 0; r < 4; ++r)
                        Cb[(size_t)(mg + r) * ldc + coloff + ng] = o[r];
                }
                if (Ch) {
                    short* Chb = Ch + (size_t)z * sC;
                    short* Clb = Cl + (size_t)z * sC;
#pragma unroll
                    for (int r = 0; r < 4; ++r) {
                        short hh = f2bf(o[r]);
                        Chb[(size_t)(mg + r) * ldc + coloff + ng] = hh;
                        Clb[(size_t)(mg + r) * ldc + coloff + ng] = f2bf(o[r] - bf2f(hh));
                    }
                }
                if (CTh) {
                    size_t cb = (size_t)z * sCT + (size_t)(mg >> 8) * 65536 + (size_t)ng * 256 + (mg & 255);
                    s16x4 hv, lv;
#pragma unroll
                    for (int r = 0; r < 4; ++r) {
                        short hh = f2bf(o[r]);
                        hv[r] = hh;
                        lv[r] = f2bf(o[r] - bf2f(hh));
                    }
                    *(s16x4*)&CTh[cb] = hv;
                    *(s16x4*)&CTl[cb] = lv;
                }
            } else {
                float bz = bias[ng];
                size_t cb = (size_t)z * sCT + (size_t)(mg >> 8) * 65536 + (size_t)ng * 256 + (mg & 255);
                s16x4 th = *(const s16x4*)&CTh[cb];
                s16x4 tl = *(const s16x4*)&CTl[cb];
                const float* Db = denom + (size_t)z * sD;
#pragma unroll
                for (int r = 0; r < 4; ++r) {
                    float sk = bf2f(th[r]) + bf2f(tl[r]);
                    float u = (v[r] + bz) / Db[mg + r];
                    float o = fmaxf(u, 0.f) + sk + bz;
                    if (C) {
                        C[(size_t)z * sC + (size_t)(mg + r) * ldc + coloff + ng] = o;
                    } else {
                        short hh = f2bf(o);
                        Ch[(size_t)z * sC + (size_t)(mg + r) * ldc + coloff + ng] = hh;
                        Cl[(size_t)z * sC + (size_t)(mg + r) * ldc + coloff + ng] = f2bf(o - bf2f(hh));
                    }
                }
            }
        }
}

// One head's masked softmax, accumulated head-sum into a. One wave per row.
__global__ void softmax_headsum_w(const float* __restrict__ scores,
                                  const unsigned char* __restrict__ pad,
                                  float* __restrict__ a, int accum) {
    int row = blockIdx.x * 4 + (threadIdx.x >> 6);
    int lane = threadIdx.x & 63;
    int b = row >> 8;
    float* arow = a + (size_t)row * 256;
    if (pad[row]) {
        if (!accum) ((float4*)arow)[lane] = make_float4(0.f, 0.f, 0.f, 0.f);
        return;
    }
    float4 s = ((const float4*)(scores + (size_t)row * 256))[lane];
    unsigned pw = *(const unsigned*)(pad + (b << 8) + lane * 4);
    if (pw & 0x000000FFu) s.x = -1e9f;
    if (pw & 0x0000FF00u) s.y = -1e9f;
    if (pw & 0x00FF0000u) s.z = -1e9f;
    if (pw & 0xFF000000u) s.w = -1e9f;
    float m = fmaxf(fmaxf(s.x, s.y), fmaxf(s.z, s.w));
#pragma unroll
    for (int o = 32; o; o >>= 1) m = fmaxf(m, __shfl_xor(m, o));
    float e0 = expf(s.x - m), e1 = expf(s.y - m), e2 = expf(s.z - m), e3 = expf(s.w - m);
    float sum = e0 + e1 + e2 + e3;
#pragma unroll
    for (int o = 32; o; o >>= 1) sum += __shfl_xor(sum, o);
    float inv = 1.f / sum;
    float4 r = make_float4(e0 * inv, e1 * inv, e2 * inv, e3 * inv);
    if (accum) {
        float4 p = ((float4*)arow)[lane];
        r.x += p.x; r.y += p.y; r.z += p.z; r.w += p.w;
    }
    ((float4*)arow)[lane] = r;
}

// ---- parallel exact top-200 radix select
__global__ void tk_init(unsigned* ghist, unsigned* prefix, int* krem) {
    int i = blockIdx.x * 256 + threadIdx.x;
    ghist[i] = 0;
    if (i < 64) { prefix[i] = 0; krem[i] = 200; }
}

__global__ void tk_hist(const float* __restrict__ a, const unsigned* __restrict__ prefix,
                        unsigned* __restrict__ ghist, int shift) {
    __shared__ unsigned h[256];
    int b = blockIdx.x >> 4, slice = blockIdx.x & 15;
    h[threadIdx.x] = 0;
    __syncthreads();
    unsigned pfx = prefix[b];
    const unsigned* ab = (const unsigned*)(a + (size_t)b * 65536) + slice * 4096;
    for (int i = threadIdx.x; i < 4096; i += 256) {
        unsigned u = ab[i];
        if ((shift == 24) || ((u >> (shift + 8)) == pfx)) atomicAdd(&h[(u >> shift) & 255], 1u);
    }
    __syncthreads();
    if (h[threadIdx.x]) atomicAdd(&ghist[b * 256 + threadIdx.x], h[threadIdx.x]);
}

__global__ void tk_pick(unsigned* __restrict__ ghist, unsigned* __restrict__ prefix,
                        int* __restrict__ krem, float* __restrict__ thr, int last) {
    __shared__ unsigned h[256];
    int b = blockIdx.x;
    h[threadIdx.x] = ghist[b * 256 + threadIdx.x];
    ghist[b * 256 + threadIdx.x] = 0;
    __syncthreads();
    if (!threadIdx.x) {
        int k = krem[b];
        unsigned c = 0;
        int bin = 255;
        for (; bin >= 0; --bin) { c += h[bin]; if ((int)c >= k) break; }
        if (bin < 0) bin = 0;
        krem[b] = k - (int)(c - h[bin]);
        unsigned p = (prefix[b] << 8) | (unsigned)bin;
        prefix[b] = p;
        if (last) thr[b] = __uint_as_float(p);
    }
}

// a2(split) = a * (sel + sel^T off-diag, 1 on diag); denom = rowsum+1
__global__ void select_apply(const float* __restrict__ a, const float* __restrict__ thr,
                             short* __restrict__ a2h, short* __restrict__ a2l,
                             float* __restrict__ denom) {
    __shared__ float sb[4];
    int row = blockIdx.x;
    int b = row >> 8, i = row & 255, j = threadIdx.x;
    const float* ab = a + (size_t)b * 65536;
    float tb = thr[b];
    float v = ab[i * 256 + j];
    float vt = ab[j * 256 + i];
    float sel = (v >= tb ? 1.f : 0.f) + (vt >= tb ? 1.f : 0.f);
    if (i == j) sel = 1.f;
    float av = v * sel;
    short hh = f2bf(av);
    a2h[(size_t)row * 256 + j] = hh;
    a2l[(size_t)row * 256 + j] = f2bf(av - bf2f(hh));
    float r = blk_sum(av, sb);
    if (!j) denom[row] = r + 1.f;
}

extern "C" void kernel_launch(void* const* d_in, const int* in_sizes, int n_in,
                              void* d_out, int out_size, void* d_ws, size_t ws_size,
                              hipStream_t stream) {
    const float* adj = (const float*)d_in[0];
    const float* x0 = (const float*)d_in[1];
    const void* mask = d_in[2];
    const float* Wls[3] = {(const float*)d_in[3], (const float*)d_in[5], (const float*)d_in[7]};
    const float* bls[3] = {(const float*)d_in[4], (const float*)d_in[6], (const float*)d_in[8]};
    const float* qws[2] = {(const float*)d_in[9], (const float*)d_in[13]};
    const float* qbs[2] = {(const float*)d_in[10], (const float*)d_in[14]};
    const float* kws[2] = {(const float*)d_in[11], (const float*)d_in[15]};
    const float* kbs[2] = {(const float*)d_in[12], (const float*)d_in[16]};

    char* base = (char*)d_ws;
    size_t cur = 0;
    auto alloc = [&](size_t bytes) -> void* {
        cur = (cur + 1023) & ~(size_t)1023;
        void* p = base + cur;
        cur += bytes;
        return p;
    };
    const size_t NROW = 16384;
    int* flags = (int*)alloc(12);
    unsigned char* pad = (unsigned char*)alloc(NROW);
    float* denom = (float*)alloc(NROW * 4);
    float* thr = (float*)alloc(256);
    unsigned* prefix = (unsigned*)alloc(256);
    int* krem = (int*)alloc(256);
    unsigned* ghist = (unsigned*)alloc(64 * 256 * 4);
    short* WTh = (short*)alloc((size_t)2304 * 256 * 2);  // packed 256x{512,768,1024}
    short* WTl = (short*)alloc((size_t)2304 * 256 * 2);
    short* qkwTh = (short*)alloc((size_t)2 * 1024 * 1024 * 2);
    short* qkwTl = (short*)alloc((size_t)2 * 1024 * 1024 * 2);
    float* qkb2 = (float*)alloc(2048 * 4);
    short* xh = (short*)alloc(NROW * 1024 * 2);
    short* xl = (short*)alloc(NROW * 1024 * 2);
    char* Sreg = (char*)alloc((size_t)64 * 65536 * 4);  // tzT split | scores alias
    float* a = (float*)alloc(NROW * 256 * 4);
    short* a2h = (short*)alloc(NROW * 256 * 2);
    short* a2l = (short*)alloc(NROW * 256 * 2);
    short* QKh = (short*)alloc((size_t)2 * NROW * 256 * 2);  // Q|K chunk, cw<=256
    short* QKl = (short*)alloc((size_t)2 * NROW * 256 * 2);
    if (ws_size < cur) return;  // clean failure instead of device fault

    short* tzTh = (short*)Sreg;
    short* tzTl = (short*)(Sreg + (size_t)64 * 65536 * 2);
    float* scores = (float*)Sreg;       // alias: tzT dead when scores live
    short* adjh = QKh;                  // alias: adj split dead once QK written
    short* adjl = QKl;
    const int Ks[3] = {512, 768, 1024};
    const long offW[3] = {0, (long)512 * 256, (long)(512 + 768) * 256};

    init_flags<<<1, 64, 0, stream>>>(flags);
    detect_mask<<<64, 256, 0, stream>>>((const unsigned int*)mask, 1048576, flags);
    extract_pad<<<64, 256, 0, stream>>>(mask, flags, pad);
    rowsum_plus1<<<16384, 256, 0, stream>>>(adj, denom);
    split_mat<<<16384, 256, 0, stream>>>(x0, 512, 512, xh, xl, 1024);
    split_mat<<<16384, 256, 0, stream>>>(adj, 256, 256, adjh, adjl, 256);
    for (int l = 0; l < 3; ++l)
        transpose_split<<<dim3(8, Ks[l] / 32), 256, 0, stream>>>(
            Wls[l], WTh + offW[l], WTl + offW[l], Ks[l], 256);

    for (int l = 0; l < 3; ++l) {
        // tzT(split) = (x @ Wl)^T per batch
        mgemm<<<dim3(2, 128, 1), 256, 0, stream>>>(
            xh, xl, WTh + offW[l], WTl + offW[l], nullptr,
            nullptr, nullptr, nullptr, tzTh, tzTl, nullptr,
            Ks[l], 256, 1024, Ks[l], 0, 0,
            0, 0, 0, 0, 0, 0, 1.f, 0);
        // fused GCN: out = relu((A@tz + b)/denom) + tz + b
        const short* Aah = (l == 0) ? adjh : a2h;
        const short* Aal = (l == 0) ? adjl : a2l;
        if (l < 2) {
            mgemm<<<dim3(2, 2, 64), 256, 0, stream>>>(
                Aah, Aal, tzTh, tzTl, bls[l],
                nullptr, xh, xl, tzTh, tzTl, denom,
                256, 256, 256, 256, 1024, Ks[l],
                65536, 65536, 0, (long)256 * 1024, 65536, 256, 1.f, 1);
        } else {
            mgemm<<<dim3(2, 2, 64), 256, 0, stream>>>(
                Aah, Aal, tzTh, tzTl, bls[l],
                (float*)d_out, nullptr, nullptr, tzTh, tzTl, denom,
                256, 256, 256, 256, 256, 0,
                65536, 65536, 0, 65536, 65536, 256, 1.f, 1);
            break;
        }

        int D = Ks[l + 1], dk = D / 8, cw = 2 * dk;
        float scale = 1.f / sqrtf((float)dk);
        transpose_split<<<dim3(D / 32, D / 32), 256, 0, stream>>>(qws[l], qkwTh, qkwTl, D, D);
        transpose_split<<<dim3(D / 32, D / 32), 256, 0, stream>>>(
            kws[l], qkwTh + (size_t)D * D, qkwTl + (size_t)D * D, D, D);
        pack_bias<<<4, 256, 0, stream>>>(qbs[l], kbs[l], qkb2, D);

        for (int c = 0; c < 4; ++c) {
            // Q and K for 2 heads in one dispatch (z: 0=Q, 1=K)
            mgemm<<<dim3((cw + 127) / 128, 128, 2), 256, 0, stream>>>(
                xh, xl, qkwTh + (size_t)c * cw * D, qkwTl + (size_t)c * cw * D, qkb2 + c * cw,
                nullptr, QKh, QKl, nullptr, nullptr, nullptr,
                D, cw, 1024, D, cw, 0,
                0, (long)D * D, 1024, (long)NROW * cw, 0, 0, 1.f, 0);
            for (int hl = 0; hl < 2; ++hl) {
                int g = c * 2 + hl;
                mgemm<<<dim3(2, 2, 64), 256, 0, stream>>>(
                    QKh + hl * dk, QKl + hl * dk,
                    QKh + (size_t)NROW * cw + hl * dk, QKl + (size_t)NROW * cw + hl * dk,
                    nullptr, scores, nullptr, nullptr, nullptr, nullptr, nullptr,
                    dk, 256, cw, cw, 256, 0,
                    (long)256 * cw, (long)256 * cw, 0, 65536, 0, 0, scale, 0);
                softmax_headsum_w<<<4096, 256, 0, stream>>>(scores, pad, a, g ? 1 : 0);
            }
        }
        tk_init<<<64, 256, 0, stream>>>(ghist, prefix, krem);
        for (int p = 0; p < 4; ++p) {
            tk_hist<<<1024, 256, 0, stream>>>(a, prefix, ghist, 24 - 8 * p);
            tk_pick<<<64, 256, 0, stream>>>(ghist, prefix, krem, thr, p == 3);
        }
        select_apply<<<16384, 256, 0, stream>>>(a, thr, a2h, a2l, denom);
    }
}

// Round 5
// 1413.947 us; speedup vs baseline: 2.8470x; 1.1586x over previous
//
#include <hip/hip_runtime.h>
#include <math.h>

// B=64, S=256, IN_DIM=512, MEM=256, LAYERS=3, HEADS=8, TOP_K=200. NROW=16384.

typedef __attribute__((ext_vector_type(8))) short s16x8;
typedef __attribute__((ext_vector_type(4))) short s16x4;
typedef __attribute__((ext_vector_type(4))) float f32x4;

__device__ __forceinline__ short f2bf(float x) {
    unsigned u = __float_as_uint(x);
    u += 0x7FFF + ((u >> 16) & 1);  // rn-even
    return (short)(u >> 16);
}
__device__ __forceinline__ float bf2f(short h) {
    return __uint_as_float(((unsigned)(unsigned short)h) << 16);
}

// async global->LDS, 16B per lane. LDS layout must be lane-contiguous (ours is).
__device__ __forceinline__ void gl2l(const void* g, void* l) {
    __builtin_amdgcn_global_load_lds(
        (const __attribute__((address_space(1))) unsigned int*)g,
        (__attribute__((address_space(3))) unsigned int*)l, 16, 0, 0);
}

__device__ __forceinline__ float blk_sum(float v, float* sb) {
#pragma unroll
    for (int o = 32; o; o >>= 1) v += __shfl_down(v, o);
    int lane = threadIdx.x & 63, w = threadIdx.x >> 6;
    if (!lane) sb[w] = v;
    __syncthreads();
    float r = sb[0] + sb[1] + sb[2] + sb[3];
    __syncthreads();
    return r;
}

__global__ void init_flags(int* flags) {
    if (threadIdx.x < 3) flags[threadIdx.x] = 0;
}

__global__ void detect_mask(const unsigned int* __restrict__ w, int nwords, int* flags) {
    int stride = gridDim.x * blockDim.x;
    int l_u8 = 0, l_f32 = 0, l_nz = 0;
    for (int i = blockIdx.x * blockDim.x + threadIdx.x; i < nwords; i += stride) {
        unsigned v = w[i];
        if (v) {
            l_nz = 1;
            if (v == 0x3F800000u) l_f32 = 1;
            else if (v > 1u) l_u8 = 1;
        }
    }
    if (__ballot(l_u8) && (threadIdx.x & 63) == 0) atomicOr(&flags[0], 1);
    if (__ballot(l_f32) && (threadIdx.x & 63) == 0) atomicOr(&flags[1], 1);
    if (__ballot(l_nz) && (threadIdx.x & 63) == 0) atomicOr(&flags[2], 1);
}

__global__ void extract_pad(const void* __restrict__ mask, const int* __restrict__ flags,
                            unsigned char* __restrict__ pad) {
    int b = blockIdx.x, i = threadIdx.x;
    int v;
    size_t idx = (size_t)b * 65536 + (size_t)i * 256;
    if (flags[0]) v = ((const unsigned char*)mask)[idx] != 0;
    else if (flags[2]) v = ((const unsigned int*)mask)[idx] != 0;
    else v = 0;
    pad[b * 256 + i] = (unsigned char)v;
}

__global__ void rowsum_plus1(const float* __restrict__ x, float* __restrict__ out) {
    __shared__ float sb[4];
    int row = blockIdx.x;
    float v = x[(size_t)row * 256 + threadIdx.x];
    float r = blk_sum(v, sb);
    if (!threadIdx.x) out[row] = r + 1.f;
}

__global__ void split_mat(const float* __restrict__ src, int ldsrc, int width,
                          short* __restrict__ dh, short* __restrict__ dl, int ldd) {
    int row = blockIdx.x;
    for (int c = threadIdx.x; c < width; c += 256) {
        float v = src[(size_t)row * ldsrc + c];
        short h = f2bf(v);
        dh[(size_t)row * ldd + c] = h;
        dl[(size_t)row * ldd + c] = f2bf(v - bf2f(h));
    }
}

// Transposed split with half-pack: logical out-row orow -> buffer row
// (orow/HR)*PSTR + (orow%HR + rowoff), ld = outld.
__global__ void transpose_split(const float* __restrict__ in,
                                short* __restrict__ outh, short* __restrict__ outl,
                                int R, int C, int HR, long PSTR, int rowoff, int outld) {
    __shared__ float tile[32][33];
    int c0 = blockIdx.x * 32, r0 = blockIdx.y * 32;
    int tx = threadIdx.x & 31, ty = threadIdx.x >> 5;
    for (int rr = ty; rr < 32; rr += 8)
        tile[rr][tx] = in[(size_t)(r0 + rr) * C + c0 + tx];
    __syncthreads();
    for (int rr = ty; rr < 32; rr += 8) {
        float v = tile[tx][rr];
        int orow = c0 + rr;
        size_t o = (size_t)(orow / HR) * PSTR + (size_t)((orow % HR) + rowoff) * outld + (r0 + tx);
        short h = f2bf(v);
        outh[o] = h;
        outl[o] = f2bf(v - bf2f(h));
    }
}

// qkb[p][0:D/2]=qb half p, qkb[p][D/2:D]=kb half p  (buffer stride 1024*2 safe)
__global__ void pack_bias2(const float* __restrict__ qb, const float* __restrict__ kb,
                           float* __restrict__ dst, int D) {
    int i = blockIdx.x * 256 + threadIdx.x;
    if (i < D) {
        int p = i / (D / 2), r = i % (D / 2);
        dst[(size_t)p * D + r] = qb[i];
        dst[(size_t)p * D + D / 2 + r] = kb[i];
    }
}

// Split-bf16 MFMA GEMM on pre-split inputs: acc = AhBh + AhBl + AlBh (fp32-class).
// A [M,K] lda, B [N,K] ldb (k-contiguous). 128x128 tile; N must be a multiple of 128.
// z decomposed: zq=z/zdiv, zr=z%zdiv; offA=zq*sA1+zr*sA2 (same B, C via sC1/sC2),
// CT offset zr*sCT, denom zr*sD.
// mode 0: o = alpha*acc + bias[ng]; optional writes: C fp32, (Ch,Cl) split, CT split
//         (layout [m/256][n][m%256]).
// mode 1: o = relu((acc+bias[ng])/denom[mg]) + (CTh+CTl)[..] + bias[ng];
//         writes C fp32 if C else (Ch,Cl) split.
__global__ __launch_bounds__(256) void mgemm(
    const short* __restrict__ Ah, const short* __restrict__ Al,
    const short* __restrict__ Bh, const short* __restrict__ Bl,
    const float* __restrict__ bias,
    float* __restrict__ C, short* __restrict__ Ch, short* __restrict__ Cl,
    short* __restrict__ CTh, short* __restrict__ CTl,
    const float* __restrict__ denom,
    int K, int lda, int ldb, int ldc, int coloff, int zdiv,
    long sA1, long sA2, long sB1, long sB2, long sC1, long sC2,
    long sCT, long sD, float alpha, int mode) {
    int z = blockIdx.z, zq = z / zdiv, zr = z % zdiv;
    const short* Ahb = Ah + (size_t)zq * sA1 + (size_t)zr * sA2;
    const short* Alb = Al + (size_t)zq * sA1 + (size_t)zr * sA2;
    const short* Bhb = Bh + (size_t)zq * sB1 + (size_t)zr * sB2;
    const short* Blb = Bl + (size_t)zq * sB1 + (size_t)zr * sB2;
    size_t offC = (size_t)zq * sC1 + (size_t)zr * sC2;
    int m0 = blockIdx.y * 128, n0 = blockIdx.x * 128;
    __shared__ short lds[16384];  // Ah[0:4096] Al[4096:] Bh[8192:] Bl[12288:]
    int t = threadIdx.x;
    int lane = t & 63, w = t >> 6;
    int wm = w >> 1, wn = w & 1;
    f32x4 acc[4][4];
#pragma unroll
    for (int i = 0; i < 4; ++i)
#pragma unroll
        for (int j = 0; j < 4; ++j)
            acc[i][j] = (f32x4){0.f, 0.f, 0.f, 0.f};

    for (int k0 = 0; k0 < K; k0 += 32) {
        __syncthreads();
#pragma unroll
        for (int p = 0; p < 2; ++p) {
            int s = t + p * 256;
            int mi = (s >> 6) * 16 + (s & 15);
            int koff = k0 + ((s >> 4) & 3) * 8;
            size_t oa = (size_t)(m0 + mi) * lda + koff;
            size_t ob = (size_t)(n0 + mi) * ldb + koff;
            gl2l(Ahb + oa, &lds[s * 8]);
            gl2l(Alb + oa, &lds[4096 + s * 8]);
            gl2l(Bhb + ob, &lds[8192 + s * 8]);
            gl2l(Blb + ob, &lds[12288 + s * 8]);
        }
        __syncthreads();
        s16x8 ah[4], al4[4], bh[4], bl4[4];
#pragma unroll
        for (int i = 0; i < 4; ++i) {
            int off = ((wm * 4 + i) * 64 + lane) * 8;
            ah[i] = *(const s16x8*)&lds[off];
            al4[i] = *(const s16x8*)&lds[4096 + off];
        }
#pragma unroll
        for (int j = 0; j < 4; ++j) {
            int off = ((wn * 4 + j) * 64 + lane) * 8;
            bh[j] = *(const s16x8*)&lds[8192 + off];
            bl4[j] = *(const s16x8*)&lds[12288 + off];
        }
#pragma unroll
        for (int i = 0; i < 4; ++i)
#pragma unroll
            for (int j = 0; j < 4; ++j) {
                acc[i][j] = __builtin_amdgcn_mfma_f32_16x16x32_bf16(ah[i], bh[j], acc[i][j], 0, 0, 0);
                acc[i][j] = __builtin_amdgcn_mfma_f32_16x16x32_bf16(ah[i], bl4[j], acc[i][j], 0, 0, 0);
                acc[i][j] = __builtin_amdgcn_mfma_f32_16x16x32_bf16(al4[i], bh[j], acc[i][j], 0, 0, 0);
            }
    }

    int col = lane & 15, quad = lane >> 4;
#pragma unroll
    for (int i = 0; i < 4; ++i)
#pragma unroll
        for (int j = 0; j < 4; ++j) {
            int mg = m0 + wm * 64 + i * 16 + quad * 4;
            int ng = n0 + wn * 64 + j * 16 + col;
            f32x4 v = acc[i][j];
            if (mode == 0) {
                float bz = bias ? bias[ng] : 0.f;
                float o[4];
#pragma unroll
                for (int r = 0; r < 4; ++r) o[r] = v[r] * alpha + bz;
                if (C) {
                    float* Cb = C + offC;
#pragma unroll
                    for (int r = 0; r < 4; ++r)
                        Cb[(size_t)(mg + r) * ldc + coloff + ng] = o[r];
                }
                if (Ch) {
                    short* Chb = Ch + offC;
                    short* Clb = Cl + offC;
#pragma unroll
                    for (int r = 0; r < 4; ++r) {
                        short hh = f2bf(o[r]);
                        Chb[(size_t)(mg + r) * ldc + coloff + ng] = hh;
                        Clb[(size_t)(mg + r) * ldc + coloff + ng] = f2bf(o[r] - bf2f(hh));
                    }
                }
                if (CTh) {
                    size_t cb = (size_t)zr * sCT + (size_t)(mg >> 8) * 65536 + (size_t)ng * 256 + (mg & 255);
                    s16x4 hv, lv;
#pragma unroll
                    for (int r = 0; r < 4; ++r) {
                        short hh = f2bf(o[r]);
                        hv[r] = hh;
                        lv[r] = f2bf(o[r] - bf2f(hh));
                    }
                    *(s16x4*)&CTh[cb] = hv;
                    *(s16x4*)&CTl[cb] = lv;
                }
            } else {
                float bz = bias[ng];
                size_t cb = (size_t)zr * sCT + (size_t)(mg >> 8) * 65536 + (size_t)ng * 256 + (mg & 255);
                s16x4 th = *(const s16x4*)&CTh[cb];
                s16x4 tl = *(const s16x4*)&CTl[cb];
                const float* Db = denom + (size_t)zr * sD;
#pragma unroll
                for (int r = 0; r < 4; ++r) {
                    float sk = bf2f(th[r]) + bf2f(tl[r]);
                    float u = (v[r] + bz) / Db[mg + r];
                    float o = fmaxf(u, 0.f) + sk + bz;
                    if (C) {
                        C[offC + (size_t)(mg + r) * ldc + coloff + ng] = o;
                    } else {
                        short hh = f2bf(o);
                        Ch[offC + (size_t)(mg + r) * ldc + coloff + ng] = hh;
                        Cl[offC + (size_t)(mg + r) * ldc + coloff + ng] = f2bf(o - bf2f(hh));
                    }
                }
            }
        }
}

// Masked softmax for TWO heads (scores [2][64][256][256]); accumulates into a.
__global__ void softmax_headsum2(const float* __restrict__ scores,
                                 const unsigned char* __restrict__ pad,
                                 float* __restrict__ a, int accum) {
    int row = blockIdx.x * 4 + (threadIdx.x >> 6);
    int lane = threadIdx.x & 63;
    int b = row >> 8;
    float* arow = a + (size_t)row * 256;
    if (pad[row]) {
        if (!accum) ((float4*)arow)[lane] = make_float4(0.f, 0.f, 0.f, 0.f);
        return;
    }
    unsigned pw = *(const unsigned*)(pad + (b << 8) + lane * 4);
    float4 racc;
    if (accum) racc = ((float4*)arow)[lane];
    else racc = make_float4(0.f, 0.f, 0.f, 0.f);
#pragma unroll
    for (int hh = 0; hh < 2; ++hh) {
        float4 s = ((const float4*)(scores + (size_t)hh * 4194304 + (size_t)row * 256))[lane];
        if (pw & 0x000000FFu) s.x = -1e9f;
        if (pw & 0x0000FF00u) s.y = -1e9f;
        if (pw & 0x00FF0000u) s.z = -1e9f;
        if (pw & 0xFF000000u) s.w = -1e9f;
        float m = fmaxf(fmaxf(s.x, s.y), fmaxf(s.z, s.w));
#pragma unroll
        for (int o = 32; o; o >>= 1) m = fmaxf(m, __shfl_xor(m, o));
        float e0 = expf(s.x - m), e1 = expf(s.y - m), e2 = expf(s.z - m), e3 = expf(s.w - m);
        float sum = e0 + e1 + e2 + e3;
#pragma unroll
        for (int o = 32; o; o >>= 1) sum += __shfl_xor(sum, o);
        float inv = 1.f / sum;
        racc.x += e0 * inv; racc.y += e1 * inv; racc.z += e2 * inv; racc.w += e3 * inv;
    }
    ((float4*)arow)[lane] = racc;
}

// ---- parallel exact top-200 radix select
__global__ void tk_init(unsigned* ghist, unsigned* prefix, int* krem) {
    int i = blockIdx.x * 256 + threadIdx.x;
    ghist[i] = 0;
    if (i < 64) { prefix[i] = 0; krem[i] = 200; }
}

__global__ void tk_hist(const float* __restrict__ a, const unsigned* __restrict__ prefix,
                        unsigned* __restrict__ ghist, int shift) {
    __shared__ unsigned h[256];
    int b = blockIdx.x >> 4, slice = blockIdx.x & 15;
    h[threadIdx.x] = 0;
    __syncthreads();
    unsigned pfx = prefix[b];
    const unsigned* ab = (const unsigned*)(a + (size_t)b * 65536) + slice * 4096;
    for (int i = threadIdx.x; i < 4096; i += 256) {
        unsigned u = ab[i];
        if ((shift == 24) || ((u >> (shift + 8)) == pfx)) atomicAdd(&h[(u >> shift) & 255], 1u);
    }
    __syncthreads();
    if (h[threadIdx.x]) atomicAdd(&ghist[b * 256 + threadIdx.x], h[threadIdx.x]);
}

__global__ void tk_pick(unsigned* __restrict__ ghist, unsigned* __restrict__ prefix,
                        int* __restrict__ krem, float* __restrict__ thr, int last) {
    __shared__ unsigned h[256];
    int b = blockIdx.x;
    h[threadIdx.x] = ghist[b * 256 + threadIdx.x];
    ghist[b * 256 + threadIdx.x] = 0;
    __syncthreads();
    if (!threadIdx.x) {
        int k = krem[b];
        unsigned c = 0;
        int bin = 255;
        for (; bin >= 0; --bin) { c += h[bin]; if ((int)c >= k) break; }
        if (bin < 0) bin = 0;
        krem[b] = k - (int)(c - h[bin]);
        unsigned p = (prefix[b] << 8) | (unsigned)bin;
        prefix[b] = p;
        if (last) thr[b] = __uint_as_float(p);
    }
}

// a2(split) = a * (sel + sel^T off-diag, 1 on diag); denom = rowsum+1
__global__ void select_apply(const float* __restrict__ a, const float* __restrict__ thr,
                             short* __restrict__ a2h, short* __restrict__ a2l,
                             float* __restrict__ denom) {
    __shared__ float sb[4];
    int row = blockIdx.x;
    int b = row >> 8, i = row & 255, j = threadIdx.x;
    const float* ab = a + (size_t)b * 65536;
    float tb = thr[b];
    float v = ab[i * 256 + j];
    float vt = ab[j * 256 + i];
    float sel = (v >= tb ? 1.f : 0.f) + (vt >= tb ? 1.f : 0.f);
    if (i == j) sel = 1.f;
    float av = v * sel;
    short hh = f2bf(av);
    a2h[(size_t)row * 256 + j] = hh;
    a2l[(size_t)row * 256 + j] = f2bf(av - bf2f(hh));
    float r = blk_sum(av, sb);
    if (!j) denom[row] = r + 1.f;
}

extern "C" void kernel_launch(void* const* d_in, const int* in_sizes, int n_in,
                              void* d_out, int out_size, void* d_ws, size_t ws_size,
                              hipStream_t stream) {
    const float* adj = (const float*)d_in[0];
    const float* x0 = (const float*)d_in[1];
    const void* mask = d_in[2];
    const float* Wls[3] = {(const float*)d_in[3], (const float*)d_in[5], (const float*)d_in[7]};
    const float* bls[3] = {(const float*)d_in[4], (const float*)d_in[6], (const float*)d_in[8]};
    const float* qws[2] = {(const float*)d_in[9], (const float*)d_in[13]};
    const float* qbs[2] = {(const float*)d_in[10], (const float*)d_in[14]};
    const float* kws[2] = {(const float*)d_in[11], (const float*)d_in[15]};
    const float* kbs[2] = {(const float*)d_in[12], (const float*)d_in[16]};

    char* base = (char*)d_ws;
    size_t cur = 0;
    auto alloc = [&](size_t bytes) -> void* {
        cur = (cur + 1023) & ~(size_t)1023;
        void* p = base + cur;
        cur += bytes;
        return p;
    };
    const size_t NROW = 16384;
    int* flags = (int*)alloc(12);
    unsigned char* pad = (unsigned char*)alloc(NROW);
    float* denom = (float*)alloc(NROW * 4);
    float* thr = (float*)alloc(256);
    unsigned* prefix = (unsigned*)alloc(256);
    int* krem = (int*)alloc(256);
    unsigned* ghist = (unsigned*)alloc(64 * 256 * 4);
    short* WTh = (short*)alloc((size_t)2304 * 256 * 2);
    short* WTl = (short*)alloc((size_t)2304 * 256 * 2);
    short* qkwPh = (short*)alloc((size_t)2 * 1024 * 1024 * 2);  // [half p][D rows][D]
    short* qkwPl = (short*)alloc((size_t)2 * 1024 * 1024 * 2);
    float* qkb = (float*)alloc((size_t)2 * 1024 * 4);
    short* xh = (short*)alloc(NROW * 1024 * 2);
    short* xl = (short*)alloc(NROW * 1024 * 2);
    char* Sreg = (char*)alloc((size_t)2 * 64 * 65536 * 4);  // tzT split | scores2 alias
    float* a = (float*)alloc(NROW * 256 * 4);
    short* a2h = (short*)alloc(NROW * 256 * 2);
    short* a2l = (short*)alloc(NROW * 256 * 2);
    short* QKh = (short*)alloc(NROW * 1024 * 2);  // half-heads Q|K [16384, D]
    short* QKl = (short*)alloc(NROW * 1024 * 2);
    if (ws_size < cur) return;  // clean failure instead of device fault

    short* tzTh = (short*)Sreg;
    short* tzTl = (short*)Sreg + (size_t)64 * 65536;
    float* scores = (float*)Sreg;  // [2][64][256][256] fp32, alias over tzT (disjoint lifetime)
    short* adjh = QKh;             // adj split dead once attention 0 starts
    short* adjl = QKl;
    const int Ks[3] = {512, 768, 1024};
    const long offW[3] = {0, (long)512 * 256, (long)(512 + 768) * 256};

    init_flags<<<1, 64, 0, stream>>>(flags);
    detect_mask<<<64, 256, 0, stream>>>((const unsigned int*)mask, 1048576, flags);
    extract_pad<<<64, 256, 0, stream>>>(mask, flags, pad);
    rowsum_plus1<<<16384, 256, 0, stream>>>(adj, denom);
    split_mat<<<16384, 256, 0, stream>>>(x0, 512, 512, xh, xl, 1024);
    split_mat<<<16384, 256, 0, stream>>>(adj, 256, 256, adjh, adjl, 256);
    for (int l = 0; l < 3; ++l)
        transpose_split<<<dim3(8, Ks[l] / 32), 256, 0, stream>>>(
            Wls[l], WTh + offW[l], WTl + offW[l], Ks[l], 256, 256, 0, 0, Ks[l]);

    for (int l = 0; l < 3; ++l) {
        int Kl = Ks[l];
        // tzT(split) = (x @ Wl)^T per batch  (CT-only write)
        mgemm<<<dim3(2, 128, 1), 256, 0, stream>>>(
            xh, xl, WTh + offW[l], WTl + offW[l], nullptr,
            nullptr, nullptr, nullptr, tzTh, tzTl, nullptr,
            Kl, 1024, Kl, 0, 0, 1,
            0, 0, 0, 0, 0, 0, 0, 0, 1.f, 0);
        // fused GCN: out = relu((A@tz + b)/denom) + tz + b
        const short* Aah = (l == 0) ? adjh : a2h;
        const short* Aal = (l == 0) ? adjl : a2l;
        if (l < 2) {
            mgemm<<<dim3(2, 2, 64), 256, 0, stream>>>(
                Aah, Aal, tzTh, tzTl, bls[l],
                nullptr, xh, xl, tzTh, tzTl, denom,
                256, 256, 256, 1024, Kl, 64,
                0, 65536, 0, 65536, 0, (long)256 * 1024, 65536, 256, 1.f, 1);
        } else {
            mgemm<<<dim3(2, 2, 64), 256, 0, stream>>>(
                Aah, Aal, tzTh, tzTl, bls[l],
                (float*)d_out, nullptr, nullptr, tzTh, tzTl, denom,
                256, 256, 256, 256, 0, 64,
                0, 65536, 0, 65536, 0, 65536, 65536, 256, 1.f, 1);
            break;
        }

        // ---- attention l (D = Ks[l+1], dk = D/8), two head-halves of 4 heads
        int D = Ks[l + 1], dk = D / 8, HD = D / 2;
        float scale = 1.f / sqrtf((float)dk);
        // packed weights: [p][0:HD]=Wq^T half p, [p][HD:D]=Wk^T half p
        transpose_split<<<dim3(D / 32, D / 32), 256, 0, stream>>>(
            qws[l], qkwPh, qkwPl, D, D, HD, (long)D * D, 0, D);
        transpose_split<<<dim3(D / 32, D / 32), 256, 0, stream>>>(
            kws[l], qkwPh, qkwPl, D, D, HD, (long)D * D, HD, D);
        pack_bias2<<<4, 256, 0, stream>>>(qbs[l], kbs[l], qkb, D);

        for (int p = 0; p < 2; ++p) {
            // QK[:,0:HD]=Q(4 heads), QK[:,HD:D]=K(4 heads): one dispatch, N=D
            mgemm<<<dim3(D / 128, 128, 1), 256, 0, stream>>>(
                xh, xl, qkwPh + (size_t)p * D * D, qkwPl + (size_t)p * D * D, qkb + (size_t)p * D,
                nullptr, QKh, QKl, nullptr, nullptr, nullptr,
                D, 1024, D, D, 0, 1,
                0, 0, 0, 0, 0, 0, 0, 0, 1.f, 0);
            for (int hp = 0; hp < 2; ++hp) {  // 2 heads per scores dispatch
                mgemm<<<dim3(2, 2, 128), 256, 0, stream>>>(
                    QKh + (size_t)(hp * 2) * dk, QKl + (size_t)(hp * 2) * dk,
                    QKh + HD + (size_t)(hp * 2) * dk, QKl + HD + (size_t)(hp * 2) * dk,
                    nullptr, scores, nullptr, nullptr, nullptr, nullptr, nullptr,
                    dk, D, D, 256, 0, 64,
                    dk, (long)256 * D, dk, (long)256 * D, (long)64 * 65536, 65536,
                    0, 0, scale, 0);
                softmax_headsum2<<<4096, 256, 0, stream>>>(scores, pad, a, (p * 2 + hp) ? 1 : 0);
            }
        }
        tk_init<<<64, 256, 0, stream>>>(ghist, prefix, krem);
        for (int pp = 0; pp < 4; ++pp) {
            tk_hist<<<1024, 256, 0, stream>>>(a, prefix, ghist, 24 - 8 * pp);
            tk_pick<<<64, 256, 0, stream>>>(ghist, prefix, krem, thr, pp == 3);
        }
        select_apply<<<16384, 256, 0, stream>>>(a, thr, a2h, a2l, denom);
    }
}

// Round 7
// 1358.289 us; speedup vs baseline: 2.9637x; 1.0410x over previous
//
#include <hip/hip_runtime.h>
#include <math.h>

// B=64, S=256, IN_DIM=512, MEM=256, LAYERS=3, HEADS=8, TOP_K=200. NROW=16384.

typedef __attribute__((ext_vector_type(8))) short s16x8;
typedef __attribute__((ext_vector_type(4))) short s16x4;
typedef __attribute__((ext_vector_type(4))) float f32x4;

__device__ __forceinline__ short f2bf(float x) {
    unsigned u = __float_as_uint(x);
    u += 0x7FFF + ((u >> 16) & 1);  // rn-even
    return (short)(u >> 16);
}
__device__ __forceinline__ float bf2f(short h) {
    return __uint_as_float(((unsigned)(unsigned short)h) << 16);
}

// async global->LDS, 16B per lane. LDS layout must be lane-contiguous (ours is).
__device__ __forceinline__ void gl2l(const void* g, void* l) {
    __builtin_amdgcn_global_load_lds(
        (const __attribute__((address_space(1))) unsigned int*)g,
        (__attribute__((address_space(3))) unsigned int*)l, 16, 0, 0);
}

__device__ __forceinline__ float blk_sum(float v, float* sb) {
#pragma unroll
    for (int o = 32; o; o >>= 1) v += __shfl_down(v, o);
    int lane = threadIdx.x & 63, w = threadIdx.x >> 6;
    if (!lane) sb[w] = v;
    __syncthreads();
    float r = sb[0] + sb[1] + sb[2] + sb[3];
    __syncthreads();
    return r;
}

__global__ void init_flags(int* flags) {
    if (threadIdx.x < 3) flags[threadIdx.x] = 0;
}

__global__ void detect_mask(const unsigned int* __restrict__ w, int nwords, int* flags) {
    int stride = gridDim.x * blockDim.x;
    int l_u8 = 0, l_f32 = 0, l_nz = 0;
    for (int i = blockIdx.x * blockDim.x + threadIdx.x; i < nwords; i += stride) {
        unsigned v = w[i];
        if (v) {
            l_nz = 1;
            if (v == 0x3F800000u) l_f32 = 1;
            else if (v > 1u) l_u8 = 1;
        }
    }
    if (__ballot(l_u8) && (threadIdx.x & 63) == 0) atomicOr(&flags[0], 1);
    if (__ballot(l_f32) && (threadIdx.x & 63) == 0) atomicOr(&flags[1], 1);
    if (__ballot(l_nz) && (threadIdx.x & 63) == 0) atomicOr(&flags[2], 1);
}

__global__ void extract_pad(const void* __restrict__ mask, const int* __restrict__ flags,
                            unsigned char* __restrict__ pad) {
    int b = blockIdx.x, i = threadIdx.x;
    int v;
    size_t idx = (size_t)b * 65536 + (size_t)i * 256;
    if (flags[0]) v = ((const unsigned char*)mask)[idx] != 0;
    else if (flags[2]) v = ((const unsigned int*)mask)[idx] != 0;
    else v = 0;
    pad[b * 256 + i] = (unsigned char)v;
}

__global__ void rowsum_plus1(const float* __restrict__ x, float* __restrict__ out) {
    __shared__ float sb[4];
    int row = blockIdx.x;
    float v = x[(size_t)row * 256 + threadIdx.x];
    float r = blk_sum(v, sb);
    if (!threadIdx.x) out[row] = r + 1.f;
}

__global__ void split_mat(const float* __restrict__ src, int ldsrc, int width,
                          short* __restrict__ dh, short* __restrict__ dl, int ldd) {
    int row = blockIdx.x;
    for (int c = threadIdx.x; c < width; c += 256) {
        float v = src[(size_t)row * ldsrc + c];
        short h = f2bf(v);
        dh[(size_t)row * ldd + c] = h;
        dl[(size_t)row * ldd + c] = f2bf(v - bf2f(h));
    }
}

// Transposed split with half-pack: logical out-row orow -> buffer row
// (orow/HR)*PSTR + (orow%HR + rowoff), ld = outld.
__global__ void transpose_split(const float* __restrict__ in,
                                short* __restrict__ outh, short* __restrict__ outl,
                                int R, int C, int HR, long PSTR, int rowoff, int outld) {
    __shared__ float tile[32][33];
    int c0 = blockIdx.x * 32, r0 = blockIdx.y * 32;
    int tx = threadIdx.x & 31, ty = threadIdx.x >> 5;
    for (int rr = ty; rr < 32; rr += 8)
        tile[rr][tx] = in[(size_t)(r0 + rr) * C + c0 + tx];
    __syncthreads();
    for (int rr = ty; rr < 32; rr += 8) {
        float v = tile[tx][rr];
        int orow = c0 + rr;
        size_t o = (size_t)(orow / HR) * PSTR + (size_t)((orow % HR) + rowoff) * outld + (r0 + tx);
        short h = f2bf(v);
        outh[o] = h;
        outl[o] = f2bf(v - bf2f(h));
    }
}

__global__ void pack_bias2(const float* __restrict__ qb, const float* __restrict__ kb,
                           float* __restrict__ dst, int D) {
    int i = blockIdx.x * 256 + threadIdx.x;
    if (i < D) {
        int p = i / (D / 2), r = i % (D / 2);
        dst[(size_t)p * D + r] = qb[i];
        dst[(size_t)p * D + D / 2 + r] = kb[i];
    }
}

// Split-bf16 MFMA GEMM on pre-split inputs: acc = AhBh + AhBl + AlBh (fp32-class).
// A [M,K] lda, B [N,K] ldb (k-contiguous). 128x128 tile; N multiple of 128.
// swap: m-tile on blockIdx.x (fast index) for tall-skinny A-locality.
// skipmode 1: early-exit if padArr[m0] (global rows). 2: batched — exit if
// padArr[zr*256+m0] or padArr[zr*256+n0] (pad is a per-batch suffix, so a
// 128-tile is all-pad iff its first row is pad).
// z: zq=z/zdiv, zr=z%zdiv; offA=zq*sA1+zr*sA2, offB=zq*sB1+zr*sB2,
// offC=zq*sC1+zr*sC2, CT offset zr*sCT, denom zr*sD.
// mode 0: o = alpha*acc + bias[ng]; optional writes C fp32 / (Ch,Cl) split / CT split
//         (layout [m/256][n][m%256]).
// mode 1: o = relu((acc+bias[ng])/denom[mg]) + (CTh+CTl)[..] + bias[ng].
__global__ __launch_bounds__(256) void mgemm(
    const short* __restrict__ Ah, const short* __restrict__ Al,
    const short* __restrict__ Bh, const short* __restrict__ Bl,
    const float* __restrict__ bias,
    float* __restrict__ C, short* __restrict__ Ch, short* __restrict__ Cl,
    short* __restrict__ CTh, short* __restrict__ CTl,
    const float* __restrict__ denom, const unsigned char* __restrict__ padArr,
    int K, int lda, int ldb, int ldc, int coloff, int zdiv,
    long sA1, long sA2, long sB1, long sB2, long sC1, long sC2,
    long sCT, long sD, float alpha, int mode, int skipmode, int swap) {
    int z = blockIdx.z, zq = z / zdiv, zr = z % zdiv;
    int m0, n0;
    if (swap) { m0 = blockIdx.x * 128; n0 = blockIdx.y * 128; }
    else      { m0 = blockIdx.y * 128; n0 = blockIdx.x * 128; }
    if (skipmode == 1 && padArr[m0]) return;
    if (skipmode == 2 && (padArr[zr * 256 + m0] || padArr[zr * 256 + n0])) return;
    const short* Ahb = Ah + (size_t)zq * sA1 + (size_t)zr * sA2;
    const short* Alb = Al + (size_t)zq * sA1 + (size_t)zr * sA2;
    const short* Bhb = Bh + (size_t)zq * sB1 + (size_t)zr * sB2;
    const short* Blb = Bl + (size_t)zq * sB1 + (size_t)zr * sB2;
    size_t offC = (size_t)zq * sC1 + (size_t)zr * sC2;
    __shared__ short lds[16384];  // Ah[0:4096] Al[4096:] Bh[8192:] Bl[12288:]
    int t = threadIdx.x;
    int lane = t & 63, w = t >> 6;
    int wm = w >> 1, wn = w & 1;
    f32x4 acc[4][4];
#pragma unroll
    for (int i = 0; i < 4; ++i)
#pragma unroll
        for (int j = 0; j < 4; ++j)
            acc[i][j] = (f32x4){0.f, 0.f, 0.f, 0.f};

    for (int k0 = 0; k0 < K; k0 += 32) {
        __syncthreads();
#pragma unroll
        for (int p = 0; p < 2; ++p) {
            int s = t + p * 256;
            int mi = (s >> 6) * 16 + (s & 15);
            int koff = k0 + ((s >> 4) & 3) * 8;
            size_t oa = (size_t)(m0 + mi) * lda + koff;
            size_t ob = (size_t)(n0 + mi) * ldb + koff;
            gl2l(Ahb + oa, &lds[s * 8]);
            gl2l(Alb + oa, &lds[4096 + s * 8]);
            gl2l(Bhb + ob, &lds[8192 + s * 8]);
            gl2l(Blb + ob, &lds[12288 + s * 8]);
        }
        __syncthreads();
        s16x8 ah[4], al4[4], bh[4], bl4[4];
#pragma unroll
        for (int i = 0; i < 4; ++i) {
            int off = ((wm * 4 + i) * 64 + lane) * 8;
            ah[i] = *(const s16x8*)&lds[off];
            al4[i] = *(const s16x8*)&lds[4096 + off];
        }
#pragma unroll
        for (int j = 0; j < 4; ++j) {
            int off = ((wn * 4 + j) * 64 + lane) * 8;
            bh[j] = *(const s16x8*)&lds[8192 + off];
            bl4[j] = *(const s16x8*)&lds[12288 + off];
        }
#pragma unroll
        for (int i = 0; i < 4; ++i)
#pragma unroll
            for (int j = 0; j < 4; ++j) {
                acc[i][j] = __builtin_amdgcn_mfma_f32_16x16x32_bf16(ah[i], bh[j], acc[i][j], 0, 0, 0);
                acc[i][j] = __builtin_amdgcn_mfma_f32_16x16x32_bf16(ah[i], bl4[j], acc[i][j], 0, 0, 0);
                acc[i][j] = __builtin_amdgcn_mfma_f32_16x16x32_bf16(al4[i], bh[j], acc[i][j], 0, 0, 0);
            }
    }

    int col = lane & 15, quad = lane >> 4;
#pragma unroll
    for (int i = 0; i < 4; ++i)
#pragma unroll
        for (int j = 0; j < 4; ++j) {
            int mg = m0 + wm * 64 + i * 16 + quad * 4;
            int ng = n0 + wn * 64 + j * 16 + col;
            f32x4 v = acc[i][j];
            if (mode == 0) {
                float bz = bias ? bias[ng] : 0.f;
                float o[4];
#pragma unroll
                for (int r = 0; r < 4; ++r) o[r] = v[r] * alpha + bz;
                if (C) {
                    float* Cb = C + offC;
#pragma unroll
                    for (int r = 0; r < 4; ++r)
                        Cb[(size_t)(mg + r) * ldc + coloff + ng] = o[r];
                }
                if (Ch) {
                    short* Chb = Ch + offC;
                    short* Clb = Cl + offC;
#pragma unroll
                    for (int r = 0; r < 4; ++r) {
                        short hh = f2bf(o[r]);
                        Chb[(size_t)(mg + r) * ldc + coloff + ng] = hh;
                        Clb[(size_t)(mg + r) * ldc + coloff + ng] = f2bf(o[r] - bf2f(hh));
                    }
                }
                if (CTh) {
                    size_t cb = (size_t)zr * sCT + (size_t)(mg >> 8) * 65536 + (size_t)ng * 256 + (mg & 255);
                    s16x4 hv, lv;
#pragma unroll
                    for (int r = 0; r < 4; ++r) {
                        short hh = f2bf(o[r]);
                        hv[r] = hh;
                        lv[r] = f2bf(o[r] - bf2f(hh));
                    }
                    *(s16x4*)&CTh[cb] = hv;
                    *(s16x4*)&CTl[cb] = lv;
                }
            } else {
                float bz = bias[ng];
                size_t cb = (size_t)zr * sCT + (size_t)(mg >> 8) * 65536 + (size_t)ng * 256 + (mg & 255);
                s16x4 th = *(const s16x4*)&CTh[cb];
                s16x4 tl = *(const s16x4*)&CTl[cb];
                const float* Db = denom + (size_t)zr * sD;
#pragma unroll
                for (int r = 0; r < 4; ++r) {
                    float sk = bf2f(th[r]) + bf2f(tl[r]);
                    float u = (v[r] + bz) / Db[mg + r];
                    float o = fmaxf(u, 0.f) + sk + bz;
                    if (C) {
                        C[offC + (size_t)(mg + r) * ldc + coloff + ng] = o;
                    } else {
                        short hh = f2bf(o);
                        Ch[offC + (size_t)(mg + r) * ldc + coloff + ng] = hh;
                        Cl[offC + (size_t)(mg + r) * ldc + coloff + ng] = f2bf(o - bf2f(hh));
                    }
                }
            }
        }
}

// Masked softmax for TWO heads (scores [2][64][256][256]); accumulates into a.
__global__ void softmax_headsum2(const float* __restrict__ scores,
                                 const unsigned char* __restrict__ pad,
                                 float* __restrict__ a, int accum) {
    int row = blockIdx.x * 4 + (threadIdx.x >> 6);
    int lane = threadIdx.x & 63;
    int b = row >> 8;
    float* arow = a + (size_t)row * 256;
    if (pad[row]) {
        if (!accum) ((float4*)arow)[lane] = make_float4(0.f, 0.f, 0.f, 0.f);
        return;
    }
    unsigned pw = *(const unsigned*)(pad + (b << 8) + lane * 4);
    float4 racc;
    if (accum) racc = ((float4*)arow)[lane];
    else racc = make_float4(0.f, 0.f, 0.f, 0.f);
#pragma unroll
    for (int hh = 0; hh < 2; ++hh) {
        float4 s = ((const float4*)(scores + (size_t)hh * 4194304 + (size_t)row * 256))[lane];
        if (pw & 0x000000FFu) s.x = -1e9f;
        if (pw & 0x0000FF00u) s.y = -1e9f;
        if (pw & 0x00FF0000u) s.z = -1e9f;
        if (pw & 0xFF000000u) s.w = -1e9f;
        float m = fmaxf(fmaxf(s.x, s.y), fmaxf(s.z, s.w));
#pragma unroll
        for (int o = 32; o; o >>= 1) m = fmaxf(m, __shfl_xor(m, o));
        float e0 = expf(s.x - m), e1 = expf(s.y - m), e2 = expf(s.z - m), e3 = expf(s.w - m);
        float sum = e0 + e1 + e2 + e3;
#pragma unroll
        for (int o = 32; o; o >>= 1) sum += __shfl_xor(sum, o);
        float inv = 1.f / sum;
        racc.x += e0 * inv; racc.y += e1 * inv; racc.z += e2 * inv; racc.w += e3 * inv;
    }
    ((float4*)arow)[lane] = racc;
}

// ---- parallel exact top-200 radix select
__global__ void tk_init(unsigned* ghist, unsigned* prefix, int* krem) {
    int i = blockIdx.x * 256 + threadIdx.x;
    ghist[i] = 0;
    if (i < 64) { prefix[i] = 0; krem[i] = 200; }
}

__global__ void tk_hist(const float* __restrict__ a, const unsigned* __restrict__ prefix,
                        unsigned* __restrict__ ghist, int shift) {
    __shared__ unsigned h[256];
    int b = blockIdx.x >> 4, slice = blockIdx.x & 15;
    h[threadIdx.x] = 0;
    __syncthreads();
    unsigned pfx = prefix[b];
    const unsigned* ab = (const unsigned*)(a + (size_t)b * 65536) + slice * 4096;
    for (int i = threadIdx.x; i < 4096; i += 256) {
        unsigned u = ab[i];
        if ((shift == 24) || ((u >> (shift + 8)) == pfx)) atomicAdd(&h[(u >> shift) & 255], 1u);
    }
    __syncthreads();
    if (h[threadIdx.x]) atomicAdd(&ghist[b * 256 + threadIdx.x], h[threadIdx.x]);
}

__global__ void tk_pick(unsigned* __restrict__ ghist, unsigned* __restrict__ prefix,
                        int* __restrict__ krem, float* __restrict__ thr, int last) {
    __shared__ unsigned h[256];
    int b = blockIdx.x;
    h[threadIdx.x] = ghist[b * 256 + threadIdx.x];
    ghist[b * 256 + threadIdx.x] = 0;
    __syncthreads();
    if (!threadIdx.x) {
        int k = krem[b];
        unsigned c = 0;
        int bin = 255;
        for (; bin >= 0; --bin) { c += h[bin]; if ((int)c >= k) break; }
        if (bin < 0) bin = 0;
        krem[b] = k - (int)(c - h[bin]);
        unsigned p = (prefix[b] << 8) | (unsigned)bin;
        prefix[b] = p;
        if (last) thr[b] = __uint_as_float(p);
    }
}

// a2(split) = a * (sel + sel^T off-diag, 1 on diag); denom = rowsum+1
__global__ void select_apply(const float* __restrict__ a, const float* __restrict__ thr,
                             short* __restrict__ a2h, short* __restrict__ a2l,
                             float* __restrict__ denom) {
    __shared__ float sb[4];
    int row = blockIdx.x;
    int b = row >> 8, i = row & 255, j = threadIdx.x;
    const float* ab = a + (size_t)b * 65536;
    float tb = thr[b];
    float v = ab[i * 256 + j];
    float vt = ab[j * 256 + i];
    float sel = (v >= tb ? 1.f : 0.f) + (vt >= tb ? 1.f : 0.f);
    if (i == j) sel = 1.f;
    float av = v * sel;
    short hh = f2bf(av);
    a2h[(size_t)row * 256 + j] = hh;
    a2l[(size_t)row * 256 + j] = f2bf(av - bf2f(hh));
    float r = blk_sum(av, sb);
    if (!j) denom[row] = r + 1.f;
}

extern "C" void kernel_launch(void* const* d_in, const int* in_sizes, int n_in,
                              void* d_out, int out_size, void* d_ws, size_t ws_size,
                              hipStream_t stream) {
    const float* adj = (const float*)d_in[0];
    const float* x0 = (const float*)d_in[1];
    const void* mask = d_in[2];
    const float* Wls[3] = {(const float*)d_in[3], (const float*)d_in[5], (const float*)d_in[7]};
    const float* bls[3] = {(const float*)d_in[4], (const float*)d_in[6], (const float*)d_in[8]};
    const float* qws[2] = {(const float*)d_in[9], (const float*)d_in[13]};
    const float* qbs[2] = {(const float*)d_in[10], (const float*)d_in[14]};
    const float* kws[2] = {(const float*)d_in[11], (const float*)d_in[15]};
    const float* kbs[2] = {(const float*)d_in[12], (const float*)d_in[16]};

    char* base = (char*)d_ws;
    size_t cur = 0;
    auto alloc = [&](size_t bytes) -> void* {
        cur = (cur + 1023) & ~(size_t)1023;
        void* p = base + cur;
        cur += bytes;
        return p;
    };
    const size_t NROW = 16384;
    int* flags = (int*)alloc(12);
    unsigned char* pad = (unsigned char*)alloc(NROW);
    float* denom = (float*)alloc(NROW * 4);
    float* thr = (float*)alloc(256);
    unsigned* prefix = (unsigned*)alloc(256);
    int* krem = (int*)alloc(256);
    unsigned* ghist = (unsigned*)alloc(64 * 256 * 4);
    short* WTh = (short*)alloc((size_t)2304 * 256 * 2);
    short* WTl = (short*)alloc((size_t)2304 * 256 * 2);
    short* qkwPh = (short*)alloc((size_t)2 * 1024 * 1024 * 2);  // [half p][D rows][D]
    short* qkwPl = (short*)alloc((size_t)2 * 1024 * 1024 * 2);
    float* qkb = (float*)alloc((size_t)2 * 1024 * 4);
    short* xh = (short*)alloc(NROW * 1024 * 2);
    short* xl = (short*)alloc(NROW * 1024 * 2);
    char* Sreg = (char*)alloc((size_t)2 * 64 * 65536 * 4);  // tzT split | scores2 alias
    float* a = (float*)alloc(NROW * 256 * 4);
    short* a2h = (short*)alloc(NROW * 256 * 2);
    short* a2l = (short*)alloc(NROW * 256 * 2);
    short* QKh = (short*)alloc(NROW * 1024 * 2);  // half-heads Q|K [16384, D]
    short* QKl = (short*)alloc(NROW * 1024 * 2);
    if (ws_size < cur) return;  // clean failure instead of device fault

    short* tzTh = (short*)Sreg;
    short* tzTl = (short*)Sreg + (size_t)64 * 65536;
    float* scores = (float*)Sreg;  // [2][64][256][256] fp32, alias over tzT (disjoint lifetime)
    short* adjh = QKh;             // adj split dead once attention 0 starts
    short* adjl = QKl;
    const int Ks[3] = {512, 768, 1024};
    const long offW[3] = {0, (long)512 * 256, (long)(512 + 768) * 256};

    init_flags<<<1, 64, 0, stream>>>(flags);
    detect_mask<<<64, 256, 0, stream>>>((const unsigned int*)mask, 1048576, flags);
    extract_pad<<<64, 256, 0, stream>>>(mask, flags, pad);
    rowsum_plus1<<<16384, 256, 0, stream>>>(adj, denom);
    split_mat<<<16384, 256, 0, stream>>>(x0, 512, 512, xh, xl, 1024);
    split_mat<<<16384, 256, 0, stream>>>(adj, 256, 256, adjh, adjl, 256);
    for (int l = 0; l < 3; ++l)
        transpose_split<<<dim3(8, Ks[l] / 32), 256, 0, stream>>>(
            Wls[l], WTh + offW[l], WTl + offW[l], Ks[l], 256, 256, 0, 0, Ks[l]);

    for (int l = 0; l < 3; ++l) {
        int Kl = Ks[l];
        // tzT(split) = (x @ Wl)^T per batch  (CT-only write), swap grid for A-locality
        mgemm<<<dim3(128, 2, 1), 256, 0, stream>>>(
            xh, xl, WTh + offW[l], WTl + offW[l], nullptr,
            nullptr, nullptr, nullptr, tzTh, tzTl, nullptr, nullptr,
            Kl, 1024, Kl, 0, 0, 1,
            0, 0, 0, 0, 0, 0, 0, 0, 1.f, 0, 0, 1);
        // fused GCN: out = relu((A@tz + b)/denom) + tz + b
        const short* Aah = (l == 0) ? adjh : a2h;
        const short* Aal = (l == 0) ? adjl : a2l;
        if (l < 2) {
            mgemm<<<dim3(2, 2, 64), 256, 0, stream>>>(
                Aah, Aal, tzTh, tzTl, bls[l],
                nullptr, xh, xl, tzTh, tzTl, denom, nullptr,
                256, 256, 256, 1024, Kl, 64,
                0, 65536, 0, 65536, 0, (long)256 * 1024, 65536, 256, 1.f, 1, 0, 0);
        } else {
            mgemm<<<dim3(2, 2, 64), 256, 0, stream>>>(
                Aah, Aal, tzTh, tzTl, bls[l],
                (float*)d_out, nullptr, nullptr, tzTh, tzTl, denom, nullptr,
                256, 256, 256, 256, 0, 64,
                0, 65536, 0, 65536, 0, 65536, 65536, 256, 1.f, 1, 0, 0);
            break;
        }

        // ---- attention l (D = Ks[l+1], dk = D/8), two head-halves of 4 heads
        int D = Ks[l + 1], dk = D / 8, HD = D / 2;
        float scale = 1.f / sqrtf((float)dk);
        // packed weights: [p][0:HD]=Wq^T half p, [p][HD:D]=Wk^T half p
        transpose_split<<<dim3(D / 32, D / 32), 256, 0, stream>>>(
            qws[l], qkwPh, qkwPl, D, D, HD, (long)D * D, 0, D);
        transpose_split<<<dim3(D / 32, D / 32), 256, 0, stream>>>(
            kws[l], qkwPh, qkwPl, D, D, HD, (long)D * D, HD, D);
        pack_bias2<<<4, 256, 0, stream>>>(qbs[l], kbs[l], qkb, D);

        for (int p = 0; p < 2; ++p) {
            // QK[:,0:HD]=Q(4 heads), QK[:,HD:D]=K(4 heads): one dispatch, N=D.
            // swap grid + skip all-pad row tiles (pad is per-batch suffix).
            mgemm<<<dim3(128, D / 128, 1), 256, 0, stream>>>(
                xh, xl, qkwPh + (size_t)p * D * D, qkwPl + (size_t)p * D * D, qkb + (size_t)p * D,
                nullptr, QKh, QKl, nullptr, nullptr, nullptr, pad,
                D, 1024, D, D, 0, 1,
                0, 0, 0, 0, 0, 0, 0, 0, 1.f, 0, 1, 1);
            for (int hp = 0; hp < 2; ++hp) {  // 2 heads per scores dispatch
                mgemm<<<dim3(2, 2, 128), 256, 0, stream>>>(
                    QKh + (size_t)(hp * 2) * dk, QKl + (size_t)(hp * 2) * dk,
                    QKh + HD + (size_t)(hp * 2) * dk, QKl + HD + (size_t)(hp * 2) * dk,
                    nullptr, scores, nullptr, nullptr, nullptr, nullptr, nullptr, pad,
                    dk, D, D, 256, 0, 64,
                    dk, (long)256 * D, dk, (long)256 * D, (long)64 * 65536, 65536,
                    0, 0, scale, 0, 2, 0);
                softmax_headsum2<<<4096, 256, 0, stream>>>(scores, pad, a, (p * 2 + hp) ? 1 : 0);
            }
        }
        tk_init<<<64, 256, 0, stream>>>(ghist, prefix, krem);
        for (int pp = 0; pp < 4; ++pp) {
            tk_hist<<<1024, 256, 0, stream>>>(a, prefix, ghist, 24 - 8 * pp);
            tk_pick<<<64, 256, 0, stream>>>(ghist, prefix, krem, thr, pp == 3);
        }
        select_apply<<<16384, 256, 0, stream>>>(a, thr, a2h, a2l, denom);
    }
}